// Round 4
// baseline (861.232 us; speedup 1.0000x reference)
//
#include <hip/hip_runtime.h>
#include <hip/hip_bf16.h>
#include <math.h>

// ---------------------------------------------------------------------------
// Expansion kernel.  Q-form fusion: out[b,uv] = sum_k Q[b,k]*LW2T[n(uv),k]
// Round 4: ONE block owns ONE 16-sample tile for ALL uv (g-split removed).
// Round-3 lesson: splitting a sample's output across XCDs caused 5.6x write
// amplification (594 MB WRITE / 668 MB FETCH = RMW line bounce through HBM,
// ~1.2 GB round-trip = the whole 614 us).  Block-exclusive output lines
// merge in the local XCD L2 and evict once.  8 waves / 512 threads,
// launch_bounds(512,4) -> 16 waves/CU, VGPR cap 128 (codegen uses ~84).
// ---------------------------------------------------------------------------

typedef short bf16x8 __attribute__((ext_vector_type(8)));
typedef float f32x4 __attribute__((ext_vector_type(4)));

static __device__ __forceinline__ short f2bf(float f) {
  unsigned u = __builtin_bit_cast(unsigned, f);
  u = u + 0x7fffu + ((u >> 16) & 1u);   // round-to-nearest-even
  return (short)(u >> 16);
}

// ---- pre-pass 1: LW2 [64][36864] f32 -> LW2T bf16 [36864][64] ------------
__global__ void k_transpose(const float* __restrict__ lw2, short* __restrict__ lw2t) {
  __shared__ float tile[64][65];
  int n0 = blockIdx.x * 64;
  int t = threadIdx.x;
#pragma unroll
  for (int k = 0; k < 16; ++k) {
    int idx = k * 256 + t;
    int c = idx >> 6, j = idx & 63;
    tile[c][j] = lw2[(size_t)c * 36864 + n0 + j];
  }
  __syncthreads();
#pragma unroll
  for (int k = 0; k < 16; ++k) {
    int idx = k * 256 + t;
    int n = idx >> 6, c = idx & 63;
    lw2t[(size_t)(n0 + n) * 64 + c] = f2bf(tile[c][n]);
  }
}

// ---- pre-pass 2: packed bias matrices ------------------------------------
__global__ void k_bias(const float* __restrict__ bw2, const float* __restrict__ lb2,
                       const float* __restrict__ bb2,
                       short* __restrict__ bb00, short* __restrict__ bb11,
                       short* __restrict__ bb01, short* __restrict__ bb10) {
  int r = blockIdx.x * 256 + threadIdx.x;
  if (r < 1024) {
    int uv = r;
    for (int k = 0; k < 64; ++k) bb00[uv * 96 + k] = f2bf(bw2[k * 1280 + uv]);
    for (int w = 0; w < 16; ++w) bb00[uv * 96 + 64 + w] = f2bf(lb2[w * 1024 + uv]);
    bb00[uv * 96 + 80] = f2bf(bb2[uv]);
    for (int k = 81; k < 96; ++k) bb00[uv * 96 + k] = 0;
  } else if (r < 1280) {
    int uv = r - 1024;
    for (int k = 0; k < 64; ++k) bb11[uv * 96 + k] = f2bf(bw2[k * 1280 + 1024 + uv]);
    for (int w = 0; w < 16; ++w) bb11[uv * 96 + 64 + w] = f2bf(lb2[16384 + w * 256 + uv]);
    bb11[uv * 96 + 80] = f2bf(bb2[1024 + uv]);
    for (int k = 81; k < 96; ++k) bb11[uv * 96 + k] = 0;
  } else if (r < 1792) {
    int uv = r - 1280;
    for (int w = 0; w < 16; ++w) bb01[uv * 32 + w] = f2bf(lb2[20480 + w * 512 + uv]);
    for (int k = 16; k < 32; ++k) bb01[uv * 32 + k] = 0;
  } else if (r < 2304) {
    int uv = r - 1792;
    for (int w = 0; w < 16; ++w) bb10[uv * 32 + w] = f2bf(lb2[28672 + w * 512 + uv]);
    for (int k = 16; k < 32; ++k) bb10[uv * 32 + k] = 0;
  }
}

// ---- pre-pass 3: per-sample h, h2, x0, x1 --------------------------------
__global__ void k_samples(const float* __restrict__ feat, const float* __restrict__ ne,
                          const float* __restrict__ W0, const float* __restrict__ W1,
                          const float* __restrict__ lw1, const float* __restrict__ lb1,
                          const float* __restrict__ bw1, const float* __restrict__ bb1,
                          float* __restrict__ H, float* __restrict__ H2,
                          float* __restrict__ X0, float* __restrict__ X1) {
  int b = blockIdx.x;
  int t = threadIdx.x;               // 192 threads
  __shared__ float sne[128];
  __shared__ float sf[320];
  if (t < 128) sne[t] = ne[(size_t)b * 128 + t];
  for (int i = t; i < 320; i += 192) sf[i] = feat[(size_t)b * 320 + i];
  __syncthreads();
  if (t < 64) {
    float a = lb1[t];
    for (int k = 0; k < 128; ++k) a += sne[k] * lw1[k * 64 + t];
    H[(size_t)b * 64 + t] = a / (1.0f + expf(-a));
  } else if (t < 128) {
    int c = t - 64;
    float a = bb1[c];
    for (int k = 0; k < 128; ++k) a += sne[k] * bw1[k * 64 + c];
    H2[(size_t)b * 64 + c] = a / (1.0f + expf(-a));
  } else if (t < 144) {
    int v = t - 128;
    float a = 0.0f;
    for (int u = 0; u < 128; ++u) a += sf[u] * W0[u * 16 + v];
    X0[(size_t)b * 16 + v] = a * 0.08838834764831845f;  // 1/sqrt(128)
  } else {
    int idx = t - 144, v = idx / 3, j = idx % 3;        // idx < 48
    float a = 0.0f;
    for (int u = 0; u < 64; ++u) a += sf[128 + u * 3 + j] * W1[u * 16 + v];
    X1[(size_t)b * 48 + v * 3 + j] = a * 0.125f;        // 1/sqrt(64)
  }
}

// ---- main kernel ----------------------------------------------------------
// A (Q matrix) in LDS, shared across 8 waves.  B streamed from global (L2).
template <int N, int NOFF, int NSTR, int NBIAS, int BBW>
static __device__ __forceinline__ void mm_frags(
    const short* __restrict__ LW2T, const short* __restrict__ BB,
    const short (&sQv)[4][32][16][8], const short* __restrict__ Abq,
    int uvbase, int col, int q, f32x4 (&acc)[N]) {
#pragma unroll
  for (int kk = 0; kk < 32; ++kk) {
    const bf16x8 A = *(const bf16x8*)&sQv[q][kk][col][0];
    int base = kk * 32 + q * 8;
    int w = base >> 6, c0 = base & 63;
    const short* brow = LW2T + (size_t)(NOFF + w * NSTR + uvbase + col) * 64 + c0;
#pragma unroll
    for (int i = 0; i < N; ++i) {
      const bf16x8 B = *(const bf16x8*)(brow + i * (16 * 64));
      acc[i] = __builtin_amdgcn_mfma_f32_16x16x32_bf16(A, B, acc[i], 0, 0, 0);
    }
  }
#pragma unroll
  for (int kk = 0; kk < NBIAS; ++kk) {
    const bf16x8 A = *(const bf16x8*)(Abq + kk * 128);
    int base = kk * 32 + q * 8;
#pragma unroll
    for (int i = 0; i < N; ++i) {
      const bf16x8 B = *(const bf16x8*)(BB + (uvbase + i * 16 + col) * BBW + base);
      acc[i] = __builtin_amdgcn_mfma_f32_16x16x32_bf16(A, B, acc[i], 0, 0, 0);
    }
  }
}

__global__ __launch_bounds__(512, 4) void k_main(
    const short* __restrict__ LW2T,
    const short* __restrict__ BB00, const short* __restrict__ BB11,
    const short* __restrict__ BB01, const short* __restrict__ BB10,
    const float* __restrict__ H, const float* __restrict__ H2,
    const float* __restrict__ X0, const float* __restrict__ X1,
    float* __restrict__ out) {
  constexpr float S00 = 0.0625f;                  // 1/16
  constexpr float S3 = 0.036084391824351614f;     // (1/sqrt(3))/16

  int b0 = blockIdx.x << 4;          // one block owns samples [b0, b0+16)
  int t = threadIdx.x;               // 512 threads = 8 waves
  int lane = t & 63, wave = t >> 6;
  int col = lane & 15, q = lane >> 4;

  __shared__ float sH[16][68];
  __shared__ float sH2[16][68];
  __shared__ float sX0[16][17];
  __shared__ float sX1[16][51];
  __shared__ short sQ[4][32][16][8];   // Q[k = kk*32+q*8+e] for sample col
  __shared__ short sAb[4][3][16][8];   // bias A-fragments (phase A)
  __shared__ short sA1[4][16][8];      // bias A-fragment (phase B)

  for (int i = t; i < 1024; i += 512) {
    int b = i >> 6, c = i & 63;
    sH[b][c]  = H[(size_t)(b0 + b) * 64 + c];
    sH2[b][c] = H2[(size_t)(b0 + b) * 64 + c];
  }
  if (t < 256) sX0[t >> 4][t & 15] = X0[(size_t)(b0 + (t >> 4)) * 16 + (t & 15)];
  for (int i = t; i < 768; i += 512)
    sX1[i / 48][i % 48] = X1[(size_t)(b0 + i / 48) * 48 + (i % 48)];
  __syncthreads();

  // =============== Phase A: Q0 = h * x0  (paths 00, 11) ===================
  for (int i = t; i < 8192; i += 512) {
    int qq = i >> 11, kk = (i >> 6) & 31, cc = (i >> 2) & 15, e2 = (i & 3) << 1;
    int k = kk * 32 + qq * 8 + e2;
    int w = k >> 6, c = k & 63;
    float xw = sX0[cc][w];
    unsigned lo = (unsigned short)f2bf(sH[cc][c] * xw);
    unsigned hi = (unsigned short)f2bf(sH[cc][c + 1] * xw);
    *(unsigned*)&sQ[qq][kk][cc][e2] = lo | (hi << 16);
  }
  for (int i = t; i < 1536; i += 512) {
    int qq = i / 384, rem = i - qq * 384;
    int kk = rem >> 7, cc = (rem >> 3) & 15, e = rem & 7;
    int k = kk * 32 + qq * 8 + e;
    float v = 0.0f;
    if (k < 64) v = sH2[cc][k];
    else if (k < 80) v = sX0[cc][k - 64];
    else if (k == 80) v = 1.0f;
    sAb[qq][kk][cc][e] = f2bf(v);
  }
  __syncthreads();

  // path00: uv = u*32+v < 1024, out (u, v), scale 1/16.  wave owns
  // uv in [wave*128, wave*128+128) as 2 chunks of 4 fragments.
#pragma unroll 1
  for (int cc2 = 0; cc2 < 2; ++cc2) {
    int uvbase = wave * 128 + cc2 * 64;
    f32x4 acc[4] = {};
    mm_frags<4, 0, 1024, 3, 96>(LW2T, BB00, sQ, &sAb[q][0][col][0],
                                uvbase, col, q, acc);
#pragma unroll
    for (int i = 0; i < 4; ++i)
#pragma unroll
      for (int ii = 0; ii < 4; ++ii) {
        size_t ob = (size_t)(b0 + q * 4 + ii) * 6400;
        int uv = uvbase + i * 16 + col;
        out[ob + (uv >> 5) * 80 + (uv & 31)] = acc[i][ii] * S00;
      }
  }

  // path11: uv = u*16+v < 256, out 3x3 diag blocks.  wave owns 2 frags.
  {
    int uvbase = wave * 32;
    f32x4 acc[2] = {};
    mm_frags<2, 16384, 256, 3, 96>(LW2T, BB11, sQ, &sAb[q][0][col][0],
                                   uvbase, col, q, acc);
#pragma unroll
    for (int i = 0; i < 2; ++i)
#pragma unroll
      for (int ii = 0; ii < 4; ++ii) {
        size_t ob = (size_t)(b0 + q * 4 + ii) * 6400;
        int uv = uvbase + i * 16 + col;
        float val = acc[i][ii] * S3;
        int u = uv >> 4, v = uv & 15;
        float* p = out + ob + (size_t)(32 + 3 * u) * 80 + (32 + 3 * v);
        p[0] = val;   p[1] = 0.f;   p[2] = 0.f;
        p[80] = 0.f;  p[81] = val;  p[82] = 0.f;
        p[160] = 0.f; p[161] = 0.f; p[162] = val;
      }
  }

  // =============== Phase B: Q1j = h * x1[:,:,j]  (paths 01, 10) ===========
#pragma unroll 1
  for (int j = 0; j < 3; ++j) {
    __syncthreads();   // all waves done reading sQ
    for (int i = t; i < 8192; i += 512) {
      int qq = i >> 11, kk = (i >> 6) & 31, cc = (i >> 2) & 15, e2 = (i & 3) << 1;
      int k = kk * 32 + qq * 8 + e2;
      int w = k >> 6, c = k & 63;
      float xw = sX1[cc][w * 3 + j];
      unsigned lo = (unsigned short)f2bf(sH[cc][c] * xw);
      unsigned hi = (unsigned short)f2bf(sH[cc][c + 1] * xw);
      *(unsigned*)&sQ[qq][kk][cc][e2] = lo | (hi << 16);
    }
    if (t < 512) {
      int i = t;
      int qq = i >> 7, cc = (i >> 3) & 15, e = i & 7;
      int k = qq * 8 + e;
      sA1[qq][cc][e] = (k < 16) ? f2bf(sX1[cc][k * 3 + j]) : (short)0;
    }
    __syncthreads();

    // path01: uv = u*16+v < 512, out (u, 32+3v+j).  wave owns 4 frags.
    {
      int uvbase = wave * 64;
      f32x4 acc[4] = {};
      mm_frags<4, 20480, 512, 1, 32>(LW2T, BB01, sQ, &sA1[q][col][0],
                                     uvbase, col, q, acc);
#pragma unroll
      for (int i = 0; i < 4; ++i)
#pragma unroll
        for (int ii = 0; ii < 4; ++ii) {
          size_t ob = (size_t)(b0 + q * 4 + ii) * 6400;
          int uv = uvbase + i * 16 + col;
          out[ob + (uv >> 4) * 80 + 32 + 3 * (uv & 15) + j] = acc[i][ii] * S3;
        }
    }
    // path10: uv = u*32+v < 512, out (32+3u+j, v).  wave owns 4 frags.
    {
      int uvbase = wave * 64;
      f32x4 acc[4] = {};
      mm_frags<4, 28672, 512, 1, 32>(LW2T, BB10, sQ, &sA1[q][col][0],
                                     uvbase, col, q, acc);
#pragma unroll
      for (int i = 0; i < 4; ++i)
#pragma unroll
        for (int ii = 0; ii < 4; ++ii) {
          size_t ob = (size_t)(b0 + q * 4 + ii) * 6400;
          int uv = uvbase + i * 16 + col;
          out[ob + (size_t)(32 + 3 * (uv >> 5) + j) * 80 + (uv & 31)] = acc[i][ii] * S3;
        }
    }
  }
}

// ---------------------------------------------------------------------------
extern "C" void kernel_launch(void* const* d_in, const int* in_sizes, int n_in,
                              void* d_out, int out_size, void* d_ws, size_t ws_size,
                              hipStream_t stream) {
  const float* feat = (const float*)d_in[0];
  const float* ne   = (const float*)d_in[1];
  const float* W0   = (const float*)d_in[2];
  const float* W1   = (const float*)d_in[3];
  const float* lw1  = (const float*)d_in[4];
  const float* lb1  = (const float*)d_in[5];
  const float* lw2  = (const float*)d_in[6];
  const float* lb2  = (const float*)d_in[7];
  const float* bw1  = (const float*)d_in[8];
  const float* bb1  = (const float*)d_in[9];
  const float* bw2  = (const float*)d_in[10];
  const float* bb2  = (const float*)d_in[11];

  char* ws = (char*)d_ws;
  short* LW2T = (short*)ws; ws += (size_t)36864 * 64 * 2;   // 4.72 MB
  short* BB00 = (short*)ws; ws += (size_t)1024 * 96 * 2;
  short* BB11 = (short*)ws; ws += (size_t)256 * 96 * 2;
  short* BB01 = (short*)ws; ws += (size_t)512 * 32 * 2;
  short* BB10 = (short*)ws; ws += (size_t)512 * 32 * 2;
  float* H  = (float*)ws;   ws += (size_t)4096 * 64 * 4;
  float* H2 = (float*)ws;   ws += (size_t)4096 * 64 * 4;
  float* X0 = (float*)ws;   ws += (size_t)4096 * 16 * 4;
  float* X1 = (float*)ws;   ws += (size_t)4096 * 48 * 4;
  (void)ws_size; (void)in_sizes; (void)n_in; (void)out_size;

  hipLaunchKernelGGL(k_transpose, dim3(576), dim3(256), 0, stream, lw2, LW2T);
  hipLaunchKernelGGL(k_bias, dim3(9), dim3(256), 0, stream, bw2, lb2, bb2,
                     BB00, BB11, BB01, BB10);
  hipLaunchKernelGGL(k_samples, dim3(4096), dim3(192), 0, stream,
                     feat, ne, W0, W1, lw1, lb1, bw1, bb1, H, H2, X0, X1);
  hipLaunchKernelGGL(k_main, dim3(256), dim3(512), 0, stream,
                     LW2T, BB00, BB11, BB01, BB10, H, H2, X0, X1, (float*)d_out);
}

// Round 6
// 206.882 us; speedup vs baseline: 4.1629x; 4.1629x over previous
//
#include <hip/hip_runtime.h>
#include <hip/hip_bf16.h>
#include <math.h>

// ---------------------------------------------------------------------------
// Expansion kernel.  Q-form fusion: out[b,uv] = sum_k Q[b,k]*LW2T[n(uv),k]
// Round 6: round-5 design with the compile error fixed (acc[j][i][ii]).
//  - launch_bounds(512,1): rounds 2/4 proved any VGPR cap <~90 forces scratch
//    spill (FETCH ~1 GB).  Grid=256 -> 1 block/CU regardless, so no cap.
//  - one block owns one 16-sample tile end-to-end (no cross-XCD output
//    line sharing -- round 3's 5.6x write amplification).
//  - phase B reads each B row ONCE for all 3 j components (3 MFMAs/load);
//    3 Q1 planes live in LDS (96 KB -- free, LDS not occupancy-limiting).
//  - path00 as one N=8 chunk: 8 independent B loads in flight per A-frag.
// ---------------------------------------------------------------------------

typedef short bf16x8 __attribute__((ext_vector_type(8)));
typedef float f32x4 __attribute__((ext_vector_type(4)));

static __device__ __forceinline__ short f2bf(float f) {
  unsigned u = __builtin_bit_cast(unsigned, f);
  u = u + 0x7fffu + ((u >> 16) & 1u);   // round-to-nearest-even
  return (short)(u >> 16);
}

// ---- pre-pass 1: LW2 [64][36864] f32 -> LW2T bf16 [36864][64] ------------
__global__ void k_transpose(const float* __restrict__ lw2, short* __restrict__ lw2t) {
  __shared__ float tile[64][65];
  int n0 = blockIdx.x * 64;
  int t = threadIdx.x;
#pragma unroll
  for (int k = 0; k < 16; ++k) {
    int idx = k * 256 + t;
    int c = idx >> 6, j = idx & 63;
    tile[c][j] = lw2[(size_t)c * 36864 + n0 + j];
  }
  __syncthreads();
#pragma unroll
  for (int k = 0; k < 16; ++k) {
    int idx = k * 256 + t;
    int n = idx >> 6, c = idx & 63;
    lw2t[(size_t)(n0 + n) * 64 + c] = f2bf(tile[c][n]);
  }
}

// ---- pre-pass 2: packed bias matrices ------------------------------------
__global__ void k_bias(const float* __restrict__ bw2, const float* __restrict__ lb2,
                       const float* __restrict__ bb2,
                       short* __restrict__ bb00, short* __restrict__ bb11,
                       short* __restrict__ bb01, short* __restrict__ bb10) {
  int r = blockIdx.x * 256 + threadIdx.x;
  if (r < 1024) {
    int uv = r;
    for (int k = 0; k < 64; ++k) bb00[uv * 96 + k] = f2bf(bw2[k * 1280 + uv]);
    for (int w = 0; w < 16; ++w) bb00[uv * 96 + 64 + w] = f2bf(lb2[w * 1024 + uv]);
    bb00[uv * 96 + 80] = f2bf(bb2[uv]);
    for (int k = 81; k < 96; ++k) bb00[uv * 96 + k] = 0;
  } else if (r < 1280) {
    int uv = r - 1024;
    for (int k = 0; k < 64; ++k) bb11[uv * 96 + k] = f2bf(bw2[k * 1280 + 1024 + uv]);
    for (int w = 0; w < 16; ++w) bb11[uv * 96 + 64 + w] = f2bf(lb2[16384 + w * 256 + uv]);
    bb11[uv * 96 + 80] = f2bf(bb2[1024 + uv]);
    for (int k = 81; k < 96; ++k) bb11[uv * 96 + k] = 0;
  } else if (r < 1792) {
    int uv = r - 1280;
    for (int w = 0; w < 16; ++w) bb01[uv * 32 + w] = f2bf(lb2[20480 + w * 512 + uv]);
    for (int k = 16; k < 32; ++k) bb01[uv * 32 + k] = 0;
  } else if (r < 2304) {
    int uv = r - 1792;
    for (int w = 0; w < 16; ++w) bb10[uv * 32 + w] = f2bf(lb2[28672 + w * 512 + uv]);
    for (int k = 16; k < 32; ++k) bb10[uv * 32 + k] = 0;
  }
}

// ---- pre-pass 3: per-sample h, h2, x0, x1 --------------------------------
__global__ void k_samples(const float* __restrict__ feat, const float* __restrict__ ne,
                          const float* __restrict__ W0, const float* __restrict__ W1,
                          const float* __restrict__ lw1, const float* __restrict__ lb1,
                          const float* __restrict__ bw1, const float* __restrict__ bb1,
                          float* __restrict__ H, float* __restrict__ H2,
                          float* __restrict__ X0, float* __restrict__ X1) {
  int b = blockIdx.x;
  int t = threadIdx.x;               // 192 threads
  __shared__ float sne[128];
  __shared__ float sf[320];
  if (t < 128) sne[t] = ne[(size_t)b * 128 + t];
  for (int i = t; i < 320; i += 192) sf[i] = feat[(size_t)b * 320 + i];
  __syncthreads();
  if (t < 64) {
    float a = lb1[t];
    for (int k = 0; k < 128; ++k) a += sne[k] * lw1[k * 64 + t];
    H[(size_t)b * 64 + t] = a / (1.0f + expf(-a));
  } else if (t < 128) {
    int c = t - 64;
    float a = bb1[c];
    for (int k = 0; k < 128; ++k) a += sne[k] * bw1[k * 64 + c];
    H2[(size_t)b * 64 + c] = a / (1.0f + expf(-a));
  } else if (t < 144) {
    int v = t - 128;
    float a = 0.0f;
    for (int u = 0; u < 128; ++u) a += sf[u] * W0[u * 16 + v];
    X0[(size_t)b * 16 + v] = a * 0.08838834764831845f;  // 1/sqrt(128)
  } else {
    int idx = t - 144, v = idx / 3, j = idx % 3;        // idx < 48
    float a = 0.0f;
    for (int u = 0; u < 64; ++u) a += sf[128 + u * 3 + j] * W1[u * 16 + v];
    X1[(size_t)b * 48 + v * 3 + j] = a * 0.125f;        // 1/sqrt(64)
  }
}

// ---- main kernel ----------------------------------------------------------
// Phase A helper: single Q plane, NBIAS bias MFMAs.
template <int N, int NOFF, int NSTR, int NBIAS, int BBW>
static __device__ __forceinline__ void mm_frags(
    const short* __restrict__ LW2T, const short* __restrict__ BB,
    const short (&sQv)[4][32][16][8], const short* __restrict__ Abq,
    int uvbase, int col, int q, f32x4 (&acc)[N]) {
#pragma unroll
  for (int kk = 0; kk < 32; ++kk) {
    const bf16x8 A = *(const bf16x8*)&sQv[q][kk][col][0];
    int base = kk * 32 + q * 8;
    int w = base >> 6, c0 = base & 63;
    const short* brow = LW2T + (size_t)(NOFF + w * NSTR + uvbase + col) * 64 + c0;
#pragma unroll
    for (int i = 0; i < N; ++i) {
      const bf16x8 B = *(const bf16x8*)(brow + i * (16 * 64));
      acc[i] = __builtin_amdgcn_mfma_f32_16x16x32_bf16(A, B, acc[i], 0, 0, 0);
    }
  }
#pragma unroll
  for (int kk = 0; kk < NBIAS; ++kk) {
    const bf16x8 A = *(const bf16x8*)(Abq + kk * 128);
    int base = kk * 32 + q * 8;
#pragma unroll
    for (int i = 0; i < N; ++i) {
      const bf16x8 B = *(const bf16x8*)(BB + (uvbase + i * 16 + col) * BBW + base);
      acc[i] = __builtin_amdgcn_mfma_f32_16x16x32_bf16(A, B, acc[i], 0, 0, 0);
    }
  }
}

// Phase B helper: 3 Q planes (j=0..2) share each B load.
template <int N, int NOFF, int NSTR, int BBW>
static __device__ __forceinline__ void mm_frags_j3(
    const short* __restrict__ LW2T, const short* __restrict__ BB,
    const short (&sQ)[3][4][32][16][8], const short (&sA1)[3][4][16][8],
    int uvbase, int col, int q, f32x4 (&acc)[3][N]) {
#pragma unroll
  for (int kk = 0; kk < 32; ++kk) {
    const bf16x8 A0 = *(const bf16x8*)&sQ[0][q][kk][col][0];
    const bf16x8 A1 = *(const bf16x8*)&sQ[1][q][kk][col][0];
    const bf16x8 A2 = *(const bf16x8*)&sQ[2][q][kk][col][0];
    int base = kk * 32 + q * 8;
    int w = base >> 6, c0 = base & 63;
    const short* brow = LW2T + (size_t)(NOFF + w * NSTR + uvbase + col) * 64 + c0;
#pragma unroll
    for (int i = 0; i < N; ++i) {
      const bf16x8 B = *(const bf16x8*)(brow + i * (16 * 64));
      acc[0][i] = __builtin_amdgcn_mfma_f32_16x16x32_bf16(A0, B, acc[0][i], 0, 0, 0);
      acc[1][i] = __builtin_amdgcn_mfma_f32_16x16x32_bf16(A1, B, acc[1][i], 0, 0, 0);
      acc[2][i] = __builtin_amdgcn_mfma_f32_16x16x32_bf16(A2, B, acc[2][i], 0, 0, 0);
    }
  }
  // bias (k < 16 only): same B row for all j
#pragma unroll
  for (int i = 0; i < N; ++i) {
    const bf16x8 B = *(const bf16x8*)(BB + (uvbase + i * 16 + col) * BBW + q * 8);
#pragma unroll
    for (int j = 0; j < 3; ++j) {
      const bf16x8 Aj = *(const bf16x8*)&sA1[j][q][col][0];
      acc[j][i] = __builtin_amdgcn_mfma_f32_16x16x32_bf16(Aj, B, acc[j][i], 0, 0, 0);
    }
  }
}

__global__ __launch_bounds__(512, 1) void k_main(
    const short* __restrict__ LW2T,
    const short* __restrict__ BB00, const short* __restrict__ BB11,
    const short* __restrict__ BB01, const short* __restrict__ BB10,
    const float* __restrict__ H, const float* __restrict__ H2,
    const float* __restrict__ X0, const float* __restrict__ X1,
    float* __restrict__ out) {
  constexpr float S00 = 0.0625f;                  // 1/16
  constexpr float S3 = 0.036084391824351614f;     // (1/sqrt(3))/16

  int b0 = blockIdx.x << 4;          // one block owns samples [b0, b0+16)
  int t = threadIdx.x;               // 512 threads = 8 waves
  int lane = t & 63, wave = t >> 6;
  int col = lane & 15, q = lane >> 4;

  __shared__ float sH[16][68];
  __shared__ float sH2[16][68];
  __shared__ float sX0[16][17];
  __shared__ float sX1[16][51];
  __shared__ short sQ[3][4][32][16][8];  // 96 KB: phase A uses plane 0
  __shared__ short sAb[4][3][16][8];     // bias A-fragments (phase A)
  __shared__ short sA1[3][4][16][8];     // bias A-fragments (phase B, per j)

  for (int i = t; i < 1024; i += 512) {
    int b = i >> 6, c = i & 63;
    sH[b][c]  = H[(size_t)(b0 + b) * 64 + c];
    sH2[b][c] = H2[(size_t)(b0 + b) * 64 + c];
  }
  if (t < 256) sX0[t >> 4][t & 15] = X0[(size_t)(b0 + (t >> 4)) * 16 + (t & 15)];
  for (int i = t; i < 768; i += 512)
    sX1[i / 48][i % 48] = X1[(size_t)(b0 + i / 48) * 48 + (i % 48)];
  __syncthreads();

  // =============== Phase A: Q0 = h * x0  (paths 00, 11) ===================
  for (int i = t; i < 8192; i += 512) {
    int qq = i >> 11, kk = (i >> 6) & 31, cc = (i >> 2) & 15, e2 = (i & 3) << 1;
    int k = kk * 32 + qq * 8 + e2;
    int w = k >> 6, c = k & 63;
    float xw = sX0[cc][w];
    unsigned lo = (unsigned short)f2bf(sH[cc][c] * xw);
    unsigned hi = (unsigned short)f2bf(sH[cc][c + 1] * xw);
    *(unsigned*)&sQ[0][qq][kk][cc][e2] = lo | (hi << 16);
  }
  for (int i = t; i < 1536; i += 512) {
    int qq = i / 384, rem = i - qq * 384;
    int kk = rem >> 7, cc = (rem >> 3) & 15, e = rem & 7;
    int k = kk * 32 + qq * 8 + e;
    float v = 0.0f;
    if (k < 64) v = sH2[cc][k];
    else if (k < 80) v = sX0[cc][k - 64];
    else if (k == 80) v = 1.0f;
    sAb[qq][kk][cc][e] = f2bf(v);
  }
  __syncthreads();

  // path00: uv = u*32+v < 1024, out (u, v), scale 1/16.  wave owns
  // uv in [wave*128, wave*128+128) as one chunk of 8 fragments.
  {
    int uvbase = wave * 128;
    f32x4 acc[8] = {};
    mm_frags<8, 0, 1024, 3, 96>(LW2T, BB00, sQ[0], &sAb[q][0][col][0],
                                uvbase, col, q, acc);
#pragma unroll
    for (int i = 0; i < 8; ++i)
#pragma unroll
      for (int ii = 0; ii < 4; ++ii) {
        size_t ob = (size_t)(b0 + q * 4 + ii) * 6400;
        int uv = uvbase + i * 16 + col;
        out[ob + (uv >> 5) * 80 + (uv & 31)] = acc[i][ii] * S00;
      }
  }

  // path11: uv = u*16+v < 256, out 3x3 diag blocks.  wave owns 2 frags.
  {
    int uvbase = wave * 32;
    f32x4 acc[2] = {};
    mm_frags<2, 16384, 256, 3, 96>(LW2T, BB11, sQ[0], &sAb[q][0][col][0],
                                   uvbase, col, q, acc);
#pragma unroll
    for (int i = 0; i < 2; ++i)
#pragma unroll
      for (int ii = 0; ii < 4; ++ii) {
        size_t ob = (size_t)(b0 + q * 4 + ii) * 6400;
        int uv = uvbase + i * 16 + col;
        float val = acc[i][ii] * S3;
        int u = uv >> 4, v = uv & 15;
        float* p = out + ob + (size_t)(32 + 3 * u) * 80 + (32 + 3 * v);
        p[0] = val;   p[1] = 0.f;   p[2] = 0.f;
        p[80] = 0.f;  p[81] = val;  p[82] = 0.f;
        p[160] = 0.f; p[161] = 0.f; p[162] = val;
      }
  }

  // =============== Phase B: Q1j = h * x1[:,:,j], all 3 j at once ==========
  __syncthreads();   // all waves done reading sQ[0]
  for (int i = t; i < 24576; i += 512) {
    int jj = i >> 13, rem = i & 8191;
    int qq = rem >> 11, kk = (rem >> 6) & 31, cc = (rem >> 2) & 15, e2 = (rem & 3) << 1;
    int k = kk * 32 + qq * 8 + e2;
    int w = k >> 6, c = k & 63;
    float xw = sX1[cc][w * 3 + jj];
    unsigned lo = (unsigned short)f2bf(sH[cc][c] * xw);
    unsigned hi = (unsigned short)f2bf(sH[cc][c + 1] * xw);
    *(unsigned*)&sQ[jj][qq][kk][cc][e2] = lo | (hi << 16);
  }
  for (int i = t; i < 1536; i += 512) {
    int jj = i >> 9, rem = i & 511;
    int qq = rem >> 7, cc = (rem >> 3) & 15, e = rem & 7;
    int k = qq * 8 + e;
    sA1[jj][qq][cc][e] = (k < 16) ? f2bf(sX1[cc][k * 3 + jj]) : (short)0;
  }
  __syncthreads();

  // path01: uv = u*16+v < 512, out (u, 32+3v+j).  wave owns 4 frags x 3 j.
  {
    int uvbase = wave * 64;
    f32x4 acc[3][4] = {};
    mm_frags_j3<4, 20480, 512, 32>(LW2T, BB01, sQ, sA1, uvbase, col, q, acc);
#pragma unroll
    for (int i = 0; i < 4; ++i)
#pragma unroll
      for (int j = 0; j < 3; ++j)
#pragma unroll
        for (int ii = 0; ii < 4; ++ii) {
          size_t ob = (size_t)(b0 + q * 4 + ii) * 6400;
          int uv = uvbase + i * 16 + col;
          out[ob + (uv >> 4) * 80 + 32 + 3 * (uv & 15) + j] = acc[j][i][ii] * S3;
        }
  }
  // path10: uv = u*32+v < 512, out (32+3u+j, v).  wave owns 4 frags x 3 j.
  {
    int uvbase = wave * 64;
    f32x4 acc[3][4] = {};
    mm_frags_j3<4, 28672, 512, 32>(LW2T, BB10, sQ, sA1, uvbase, col, q, acc);
#pragma unroll
    for (int i = 0; i < 4; ++i)
#pragma unroll
      for (int j = 0; j < 3; ++j)
#pragma unroll
        for (int ii = 0; ii < 4; ++ii) {
          size_t ob = (size_t)(b0 + q * 4 + ii) * 6400;
          int uv = uvbase + i * 16 + col;
          out[ob + (size_t)(32 + 3 * (uv >> 5) + j) * 80 + (uv & 31)] = acc[j][i][ii] * S3;
        }
  }
}

// ---------------------------------------------------------------------------
extern "C" void kernel_launch(void* const* d_in, const int* in_sizes, int n_in,
                              void* d_out, int out_size, void* d_ws, size_t ws_size,
                              hipStream_t stream) {
  const float* feat = (const float*)d_in[0];
  const float* ne   = (const float*)d_in[1];
  const float* W0   = (const float*)d_in[2];
  const float* W1   = (const float*)d_in[3];
  const float* lw1  = (const float*)d_in[4];
  const float* lb1  = (const float*)d_in[5];
  const float* lw2  = (const float*)d_in[6];
  const float* lb2  = (const float*)d_in[7];
  const float* bw1  = (const float*)d_in[8];
  const float* bb1  = (const float*)d_in[9];
  const float* bw2  = (const float*)d_in[10];
  const float* bb2  = (const float*)d_in[11];

  char* ws = (char*)d_ws;
  short* LW2T = (short*)ws; ws += (size_t)36864 * 64 * 2;   // 4.72 MB
  short* BB00 = (short*)ws; ws += (size_t)1024 * 96 * 2;
  short* BB11 = (short*)ws; ws += (size_t)256 * 96 * 2;
  short* BB01 = (short*)ws; ws += (size_t)512 * 32 * 2;
  short* BB10 = (short*)ws; ws += (size_t)512 * 32 * 2;
  float* H  = (float*)ws;   ws += (size_t)4096 * 64 * 4;
  float* H2 = (float*)ws;   ws += (size_t)4096 * 64 * 4;
  float* X0 = (float*)ws;   ws += (size_t)4096 * 16 * 4;
  float* X1 = (float*)ws;   ws += (size_t)4096 * 48 * 4;
  (void)ws_size; (void)in_sizes; (void)n_in; (void)out_size;

  hipLaunchKernelGGL(k_transpose, dim3(576), dim3(256), 0, stream, lw2, LW2T);
  hipLaunchKernelGGL(k_bias, dim3(9), dim3(256), 0, stream, bw2, lb2, bb2,
                     BB00, BB11, BB01, BB10);
  hipLaunchKernelGGL(k_samples, dim3(4096), dim3(192), 0, stream,
                     feat, ne, W0, W1, lw1, lb1, bw1, bb1, H, H2, X0, X1);
  hipLaunchKernelGGL(k_main, dim3(256), dim3(512), 0, stream,
                     LW2T, BB00, BB11, BB01, BB10, H, H2, X0, X1, (float*)d_out);
}

// Round 7
// 195.762 us; speedup vs baseline: 4.3994x; 1.0568x over previous
//
#include <hip/hip_runtime.h>
#include <hip/hip_bf16.h>
#include <math.h>

// ---------------------------------------------------------------------------
// Expansion kernel.  Q-form fusion: out[b,uv] = sum_k Q[b,k]*LW2T[n(uv),k]
// Round 7: round-6 structure + explicit depth-2 register pipeline for the
// B-stream.  Round-6 counters: 191 cy/MFMA with MfmaUtil 8.3% -> B loads
// were serialized at L2 latency.  Two named B buffers (Ba/Bb), loads for
// kk+2 issued before MFMAs of kk, so ~8-16 loads stay outstanding per wave
// and the compiler can emit counted vmcnt waits.  Floor: B stream 1.2 GB
// from L2 (~35us) + 105 MB out writes (~17us overlapped).
//  - launch_bounds(512,1): VGPR cap <~90 forces scratch spill (rounds 2/4).
//  - one block owns one 16-sample tile end-to-end (round 3: cross-XCD
//    output line sharing = 5.6x write amplification).
//  - phase B reads each B row ONCE for all 3 j components (3 MFMAs/load).
// ---------------------------------------------------------------------------

typedef short bf16x8 __attribute__((ext_vector_type(8)));
typedef float f32x4 __attribute__((ext_vector_type(4)));

static __device__ __forceinline__ short f2bf(float f) {
  unsigned u = __builtin_bit_cast(unsigned, f);
  u = u + 0x7fffu + ((u >> 16) & 1u);   // round-to-nearest-even
  return (short)(u >> 16);
}

// ---- pre-pass 1: LW2 [64][36864] f32 -> LW2T bf16 [36864][64] ------------
__global__ void k_transpose(const float* __restrict__ lw2, short* __restrict__ lw2t) {
  __shared__ float tile[64][65];
  int n0 = blockIdx.x * 64;
  int t = threadIdx.x;
#pragma unroll
  for (int k = 0; k < 16; ++k) {
    int idx = k * 256 + t;
    int c = idx >> 6, j = idx & 63;
    tile[c][j] = lw2[(size_t)c * 36864 + n0 + j];
  }
  __syncthreads();
#pragma unroll
  for (int k = 0; k < 16; ++k) {
    int idx = k * 256 + t;
    int n = idx >> 6, c = idx & 63;
    lw2t[(size_t)(n0 + n) * 64 + c] = f2bf(tile[c][n]);
  }
}

// ---- pre-pass 2: packed bias matrices ------------------------------------
__global__ void k_bias(const float* __restrict__ bw2, const float* __restrict__ lb2,
                       const float* __restrict__ bb2,
                       short* __restrict__ bb00, short* __restrict__ bb11,
                       short* __restrict__ bb01, short* __restrict__ bb10) {
  int r = blockIdx.x * 256 + threadIdx.x;
  if (r < 1024) {
    int uv = r;
    for (int k = 0; k < 64; ++k) bb00[uv * 96 + k] = f2bf(bw2[k * 1280 + uv]);
    for (int w = 0; w < 16; ++w) bb00[uv * 96 + 64 + w] = f2bf(lb2[w * 1024 + uv]);
    bb00[uv * 96 + 80] = f2bf(bb2[uv]);
    for (int k = 81; k < 96; ++k) bb00[uv * 96 + k] = 0;
  } else if (r < 1280) {
    int uv = r - 1024;
    for (int k = 0; k < 64; ++k) bb11[uv * 96 + k] = f2bf(bw2[k * 1280 + 1024 + uv]);
    for (int w = 0; w < 16; ++w) bb11[uv * 96 + 64 + w] = f2bf(lb2[16384 + w * 256 + uv]);
    bb11[uv * 96 + 80] = f2bf(bb2[1024 + uv]);
    for (int k = 81; k < 96; ++k) bb11[uv * 96 + k] = 0;
  } else if (r < 1792) {
    int uv = r - 1280;
    for (int w = 0; w < 16; ++w) bb01[uv * 32 + w] = f2bf(lb2[20480 + w * 512 + uv]);
    for (int k = 16; k < 32; ++k) bb01[uv * 32 + k] = 0;
  } else if (r < 2304) {
    int uv = r - 1792;
    for (int w = 0; w < 16; ++w) bb10[uv * 32 + w] = f2bf(lb2[28672 + w * 512 + uv]);
    for (int k = 16; k < 32; ++k) bb10[uv * 32 + k] = 0;
  }
}

// ---- pre-pass 3: per-sample h, h2, x0, x1 --------------------------------
__global__ void k_samples(const float* __restrict__ feat, const float* __restrict__ ne,
                          const float* __restrict__ W0, const float* __restrict__ W1,
                          const float* __restrict__ lw1, const float* __restrict__ lb1,
                          const float* __restrict__ bw1, const float* __restrict__ bb1,
                          float* __restrict__ H, float* __restrict__ H2,
                          float* __restrict__ X0, float* __restrict__ X1) {
  int b = blockIdx.x;
  int t = threadIdx.x;               // 192 threads
  __shared__ float sne[128];
  __shared__ float sf[320];
  if (t < 128) sne[t] = ne[(size_t)b * 128 + t];
  for (int i = t; i < 320; i += 192) sf[i] = feat[(size_t)b * 320 + i];
  __syncthreads();
  if (t < 64) {
    float a = lb1[t];
    for (int k = 0; k < 128; ++k) a += sne[k] * lw1[k * 64 + t];
    H[(size_t)b * 64 + t] = a / (1.0f + expf(-a));
  } else if (t < 128) {
    int c = t - 64;
    float a = bb1[c];
    for (int k = 0; k < 128; ++k) a += sne[k] * bw1[k * 64 + c];
    H2[(size_t)b * 64 + c] = a / (1.0f + expf(-a));
  } else if (t < 144) {
    int v = t - 128;
    float a = 0.0f;
    for (int u = 0; u < 128; ++u) a += sf[u] * W0[u * 16 + v];
    X0[(size_t)b * 16 + v] = a * 0.08838834764831845f;  // 1/sqrt(128)
  } else {
    int idx = t - 144, v = idx / 3, j = idx % 3;        // idx < 48
    float a = 0.0f;
    for (int u = 0; u < 64; ++u) a += sf[128 + u * 3 + j] * W1[u * 16 + v];
    X1[(size_t)b * 48 + v * 3 + j] = a * 0.125f;        // 1/sqrt(64)
  }
}

// ---- main kernel ----------------------------------------------------------
// Phase A helper: single Q plane, NBIAS bias MFMAs.  Depth-2 B pipeline.
template <int N, int NOFF, int NSTR, int NBIAS, int BBW>
static __device__ __forceinline__ void mm_frags(
    const short* __restrict__ LW2T, const short* __restrict__ BB,
    const short (&sQv)[4][32][16][8], const short* __restrict__ Abq,
    int uvbase, int col, int q, f32x4 (&acc)[N]) {
  const short* lw = LW2T + (size_t)(NOFF + uvbase + col) * 64;
  auto bptr = [&](int kk, int i) -> const bf16x8* {
    int base = kk * 32 + q * 8;
    int w = base >> 6, c0 = base & 63;
    return (const bf16x8*)(lw + ((size_t)w * NSTR + i * 16) * 64 + c0);
  };
  bf16x8 Ba[N], Bb[N];
#pragma unroll
  for (int i = 0; i < N; ++i) Ba[i] = *bptr(0, i);
#pragma unroll
  for (int i = 0; i < N; ++i) Bb[i] = *bptr(1, i);
#pragma unroll
  for (int k2 = 0; k2 < 16; ++k2) {
    const int kA = 2 * k2, kB = 2 * k2 + 1;
    {
      const bf16x8 A = *(const bf16x8*)&sQv[q][kA][col][0];
#pragma unroll
      for (int i = 0; i < N; ++i)
        acc[i] = __builtin_amdgcn_mfma_f32_16x16x32_bf16(A, Ba[i], acc[i], 0, 0, 0);
    }
    if (kA + 2 < 32) {
#pragma unroll
      for (int i = 0; i < N; ++i) Ba[i] = *bptr(kA + 2, i);
    }
    {
      const bf16x8 A = *(const bf16x8*)&sQv[q][kB][col][0];
#pragma unroll
      for (int i = 0; i < N; ++i)
        acc[i] = __builtin_amdgcn_mfma_f32_16x16x32_bf16(A, Bb[i], acc[i], 0, 0, 0);
    }
    if (kB + 2 < 32) {
#pragma unroll
      for (int i = 0; i < N; ++i) Bb[i] = *bptr(kB + 2, i);
    }
  }
#pragma unroll
  for (int kk = 0; kk < NBIAS; ++kk) {
    const bf16x8 A = *(const bf16x8*)(Abq + kk * 128);
    int base = kk * 32 + q * 8;
#pragma unroll
    for (int i = 0; i < N; ++i) {
      const bf16x8 B = *(const bf16x8*)(BB + (uvbase + i * 16 + col) * BBW + base);
      acc[i] = __builtin_amdgcn_mfma_f32_16x16x32_bf16(A, B, acc[i], 0, 0, 0);
    }
  }
}

// Phase B helper: 3 Q planes (j=0..2) share each B load.  Depth-2 pipeline.
template <int N, int NOFF, int NSTR, int BBW>
static __device__ __forceinline__ void mm_frags_j3(
    const short* __restrict__ LW2T, const short* __restrict__ BB,
    const short (&sQ)[3][4][32][16][8], const short (&sA1)[3][4][16][8],
    int uvbase, int col, int q, f32x4 (&acc)[3][N]) {
  const short* lw = LW2T + (size_t)(NOFF + uvbase + col) * 64;
  auto bptr = [&](int kk, int i) -> const bf16x8* {
    int base = kk * 32 + q * 8;
    int w = base >> 6, c0 = base & 63;
    return (const bf16x8*)(lw + ((size_t)w * NSTR + i * 16) * 64 + c0);
  };
  bf16x8 Ba[N], Bb[N];
#pragma unroll
  for (int i = 0; i < N; ++i) Ba[i] = *bptr(0, i);
#pragma unroll
  for (int i = 0; i < N; ++i) Bb[i] = *bptr(1, i);
#pragma unroll
  for (int k2 = 0; k2 < 16; ++k2) {
    const int kA = 2 * k2, kB = 2 * k2 + 1;
    {
      const bf16x8 A0 = *(const bf16x8*)&sQ[0][q][kA][col][0];
      const bf16x8 A1 = *(const bf16x8*)&sQ[1][q][kA][col][0];
      const bf16x8 A2 = *(const bf16x8*)&sQ[2][q][kA][col][0];
#pragma unroll
      for (int i = 0; i < N; ++i) {
        acc[0][i] = __builtin_amdgcn_mfma_f32_16x16x32_bf16(A0, Ba[i], acc[0][i], 0, 0, 0);
        acc[1][i] = __builtin_amdgcn_mfma_f32_16x16x32_bf16(A1, Ba[i], acc[1][i], 0, 0, 0);
        acc[2][i] = __builtin_amdgcn_mfma_f32_16x16x32_bf16(A2, Ba[i], acc[2][i], 0, 0, 0);
      }
    }
    if (kA + 2 < 32) {
#pragma unroll
      for (int i = 0; i < N; ++i) Ba[i] = *bptr(kA + 2, i);
    }
    {
      const bf16x8 A0 = *(const bf16x8*)&sQ[0][q][kB][col][0];
      const bf16x8 A1 = *(const bf16x8*)&sQ[1][q][kB][col][0];
      const bf16x8 A2 = *(const bf16x8*)&sQ[2][q][kB][col][0];
#pragma unroll
      for (int i = 0; i < N; ++i) {
        acc[0][i] = __builtin_amdgcn_mfma_f32_16x16x32_bf16(A0, Bb[i], acc[0][i], 0, 0, 0);
        acc[1][i] = __builtin_amdgcn_mfma_f32_16x16x32_bf16(A1, Bb[i], acc[1][i], 0, 0, 0);
        acc[2][i] = __builtin_amdgcn_mfma_f32_16x16x32_bf16(A2, Bb[i], acc[2][i], 0, 0, 0);
      }
    }
    if (kB + 2 < 32) {
#pragma unroll
      for (int i = 0; i < N; ++i) Bb[i] = *bptr(kB + 2, i);
    }
  }
  // bias (k < 16 only): same B row for all j
#pragma unroll
  for (int i = 0; i < N; ++i) {
    const bf16x8 B = *(const bf16x8*)(BB + (uvbase + i * 16 + col) * BBW + q * 8);
#pragma unroll
    for (int j = 0; j < 3; ++j) {
      const bf16x8 Aj = *(const bf16x8*)&sA1[j][q][col][0];
      acc[j][i] = __builtin_amdgcn_mfma_f32_16x16x32_bf16(Aj, B, acc[j][i], 0, 0, 0);
    }
  }
}

__global__ __launch_bounds__(512, 1) void k_main(
    const short* __restrict__ LW2T,
    const short* __restrict__ BB00, const short* __restrict__ BB11,
    const short* __restrict__ BB01, const short* __restrict__ BB10,
    const float* __restrict__ H, const float* __restrict__ H2,
    const float* __restrict__ X0, const float* __restrict__ X1,
    float* __restrict__ out) {
  constexpr float S00 = 0.0625f;                  // 1/16
  constexpr float S3 = 0.036084391824351614f;     // (1/sqrt(3))/16

  int b0 = blockIdx.x << 4;          // one block owns samples [b0, b0+16)
  int t = threadIdx.x;               // 512 threads = 8 waves
  int lane = t & 63, wave = t >> 6;
  int col = lane & 15, q = lane >> 4;

  __shared__ float sH[16][68];
  __shared__ float sH2[16][68];
  __shared__ float sX0[16][17];
  __shared__ float sX1[16][51];
  __shared__ short sQ[3][4][32][16][8];  // 96 KB: phase A uses plane 0
  __shared__ short sAb[4][3][16][8];     // bias A-fragments (phase A)
  __shared__ short sA1[3][4][16][8];     // bias A-fragments (phase B, per j)

  for (int i = t; i < 1024; i += 512) {
    int b = i >> 6, c = i & 63;
    sH[b][c]  = H[(size_t)(b0 + b) * 64 + c];
    sH2[b][c] = H2[(size_t)(b0 + b) * 64 + c];
  }
  if (t < 256) sX0[t >> 4][t & 15] = X0[(size_t)(b0 + (t >> 4)) * 16 + (t & 15)];
  for (int i = t; i < 768; i += 512)
    sX1[i / 48][i % 48] = X1[(size_t)(b0 + i / 48) * 48 + (i % 48)];
  __syncthreads();

  // =============== Phase A: Q0 = h * x0  (paths 00, 11) ===================
  for (int i = t; i < 8192; i += 512) {
    int qq = i >> 11, kk = (i >> 6) & 31, cc = (i >> 2) & 15, e2 = (i & 3) << 1;
    int k = kk * 32 + qq * 8 + e2;
    int w = k >> 6, c = k & 63;
    float xw = sX0[cc][w];
    unsigned lo = (unsigned short)f2bf(sH[cc][c] * xw);
    unsigned hi = (unsigned short)f2bf(sH[cc][c + 1] * xw);
    *(unsigned*)&sQ[0][qq][kk][cc][e2] = lo | (hi << 16);
  }
  for (int i = t; i < 1536; i += 512) {
    int qq = i / 384, rem = i - qq * 384;
    int kk = rem >> 7, cc = (rem >> 3) & 15, e = rem & 7;
    int k = kk * 32 + qq * 8 + e;
    float v = 0.0f;
    if (k < 64) v = sH2[cc][k];
    else if (k < 80) v = sX0[cc][k - 64];
    else if (k == 80) v = 1.0f;
    sAb[qq][kk][cc][e] = f2bf(v);
  }
  __syncthreads();

  // path00: uv = u*32+v < 1024, out (u, v), scale 1/16.  wave owns
  // uv in [wave*128, wave*128+128) as one chunk of 8 fragments.
  {
    int uvbase = wave * 128;
    f32x4 acc[8] = {};
    mm_frags<8, 0, 1024, 3, 96>(LW2T, BB00, sQ[0], &sAb[q][0][col][0],
                                uvbase, col, q, acc);
#pragma unroll
    for (int i = 0; i < 8; ++i)
#pragma unroll
      for (int ii = 0; ii < 4; ++ii) {
        size_t ob = (size_t)(b0 + q * 4 + ii) * 6400;
        int uv = uvbase + i * 16 + col;
        out[ob + (uv >> 5) * 80 + (uv & 31)] = acc[i][ii] * S00;
      }
  }

  // path11: uv = u*16+v < 256, out 3x3 diag blocks.  wave owns 2 frags.
  {
    int uvbase = wave * 32;
    f32x4 acc[2] = {};
    mm_frags<2, 16384, 256, 3, 96>(LW2T, BB11, sQ[0], &sAb[q][0][col][0],
                                   uvbase, col, q, acc);
#pragma unroll
    for (int i = 0; i < 2; ++i)
#pragma unroll
      for (int ii = 0; ii < 4; ++ii) {
        size_t ob = (size_t)(b0 + q * 4 + ii) * 6400;
        int uv = uvbase + i * 16 + col;
        float val = acc[i][ii] * S3;
        int u = uv >> 4, v = uv & 15;
        float* p = out + ob + (size_t)(32 + 3 * u) * 80 + (32 + 3 * v);
        p[0] = val;   p[1] = 0.f;   p[2] = 0.f;
        p[80] = 0.f;  p[81] = val;  p[82] = 0.f;
        p[160] = 0.f; p[161] = 0.f; p[162] = val;
      }
  }

  // =============== Phase B: Q1j = h * x1[:,:,j], all 3 j at once ==========
  __syncthreads();   // all waves done reading sQ[0]
  for (int i = t; i < 24576; i += 512) {
    int jj = i >> 13, rem = i & 8191;
    int qq = rem >> 11, kk = (rem >> 6) & 31, cc = (rem >> 2) & 15, e2 = (rem & 3) << 1;
    int k = kk * 32 + qq * 8 + e2;
    int w = k >> 6, c = k & 63;
    float xw = sX1[cc][w * 3 + jj];
    unsigned lo = (unsigned short)f2bf(sH[cc][c] * xw);
    unsigned hi = (unsigned short)f2bf(sH[cc][c + 1] * xw);
    *(unsigned*)&sQ[jj][qq][kk][cc][e2] = lo | (hi << 16);
  }
  for (int i = t; i < 1536; i += 512) {
    int jj = i >> 9, rem = i & 511;
    int qq = rem >> 7, cc = (rem >> 3) & 15, e = rem & 7;
    int k = qq * 8 + e;
    sA1[jj][qq][cc][e] = (k < 16) ? f2bf(sX1[cc][k * 3 + jj]) : (short)0;
  }
  __syncthreads();

  // path01: uv = u*16+v < 512, out (u, 32+3v+j).  wave owns 4 frags x 3 j.
  {
    int uvbase = wave * 64;
    f32x4 acc[3][4] = {};
    mm_frags_j3<4, 20480, 512, 32>(LW2T, BB01, sQ, sA1, uvbase, col, q, acc);
#pragma unroll
    for (int i = 0; i < 4; ++i)
#pragma unroll
      for (int j = 0; j < 3; ++j)
#pragma unroll
        for (int ii = 0; ii < 4; ++ii) {
          size_t ob = (size_t)(b0 + q * 4 + ii) * 6400;
          int uv = uvbase + i * 16 + col;
          out[ob + (uv >> 4) * 80 + 32 + 3 * (uv & 15) + j] = acc[j][i][ii] * S3;
        }
  }
  // path10: uv = u*32+v < 512, out (32+3u+j, v).  wave owns 4 frags x 3 j.
  {
    int uvbase = wave * 64;
    f32x4 acc[3][4] = {};
    mm_frags_j3<4, 28672, 512, 32>(LW2T, BB10, sQ, sA1, uvbase, col, q, acc);
#pragma unroll
    for (int i = 0; i < 4; ++i)
#pragma unroll
      for (int j = 0; j < 3; ++j)
#pragma unroll
        for (int ii = 0; ii < 4; ++ii) {
          size_t ob = (size_t)(b0 + q * 4 + ii) * 6400;
          int uv = uvbase + i * 16 + col;
          out[ob + (size_t)(32 + 3 * (uv >> 5) + j) * 80 + (uv & 31)] = acc[j][i][ii] * S3;
        }
  }
}

// ---------------------------------------------------------------------------
extern "C" void kernel_launch(void* const* d_in, const int* in_sizes, int n_in,
                              void* d_out, int out_size, void* d_ws, size_t ws_size,
                              hipStream_t stream) {
  const float* feat = (const float*)d_in[0];
  const float* ne   = (const float*)d_in[1];
  const float* W0   = (const float*)d_in[2];
  const float* W1   = (const float*)d_in[3];
  const float* lw1  = (const float*)d_in[4];
  const float* lb1  = (const float*)d_in[5];
  const float* lw2  = (const float*)d_in[6];
  const float* lb2  = (const float*)d_in[7];
  const float* bw1  = (const float*)d_in[8];
  const float* bb1  = (const float*)d_in[9];
  const float* bw2  = (const float*)d_in[10];
  const float* bb2  = (const float*)d_in[11];

  char* ws = (char*)d_ws;
  short* LW2T = (short*)ws; ws += (size_t)36864 * 64 * 2;   // 4.72 MB
  short* BB00 = (short*)ws; ws += (size_t)1024 * 96 * 2;
  short* BB11 = (short*)ws; ws += (size_t)256 * 96 * 2;
  short* BB01 = (short*)ws; ws += (size_t)512 * 32 * 2;
  short* BB10 = (short*)ws; ws += (size_t)512 * 32 * 2;
  float* H  = (float*)ws;   ws += (size_t)4096 * 64 * 4;
  float* H2 = (float*)ws;   ws += (size_t)4096 * 64 * 4;
  float* X0 = (float*)ws;   ws += (size_t)4096 * 16 * 4;
  float* X1 = (float*)ws;   ws += (size_t)4096 * 48 * 4;
  (void)ws_size; (void)in_sizes; (void)n_in; (void)out_size;

  hipLaunchKernelGGL(k_transpose, dim3(576), dim3(256), 0, stream, lw2, LW2T);
  hipLaunchKernelGGL(k_bias, dim3(9), dim3(256), 0, stream, bw2, lb2, bb2,
                     BB00, BB11, BB01, BB10);
  hipLaunchKernelGGL(k_samples, dim3(4096), dim3(192), 0, stream,
                     feat, ne, W0, W1, lw1, lb1, bw1, bb1, H, H2, X0, X1);
  hipLaunchKernelGGL(k_main, dim3(256), dim3(512), 0, stream,
                     LW2T, BB00, BB11, BB01, BB10, H, H2, X0, X1, (float*)d_out);
}

// Round 8
// 178.387 us; speedup vs baseline: 4.8279x; 1.0974x over previous
//
#include <hip/hip_runtime.h>
#include <hip/hip_bf16.h>
#include <math.h>

// ---------------------------------------------------------------------------
// Expansion kernel.  Q-form fusion: out[b,uv] = sum_k Q[b,k]*LW2T[n(uv),k]
// Round 8: arithmetic-intensity restructure.  Block = 32 samples x uv-HALF
// (grid 256 = 128 tiles x 2 halves).  Two sample-group Q-planes in LDS ->
// 2 MFMAs per B-load in phase A; phase B fuses {2 groups x 2 j} = 4 MFMAs
// per B-load (j passes {0,1} then {2}).  B-load count 1.26M -> 466k.
// uv-half split is by OUTPUT ROWS -> halves share ~no out lines (round-3
// lesson); both halves of a tile pinned to one XCD via blockIdx%8.
// A-planes stored [kk][col][q][e]: wave reads 1024 contiguous B, no bank
// aliasing.  launch_bounds(512,1) (VGPR cap < ~90 spills, rounds 2/4).
// ---------------------------------------------------------------------------

typedef short bf16x8 __attribute__((ext_vector_type(8)));
typedef float f32x4 __attribute__((ext_vector_type(4)));

static __device__ __forceinline__ short f2bf(float f) {
  unsigned u = __builtin_bit_cast(unsigned, f);
  u = u + 0x7fffu + ((u >> 16) & 1u);   // round-to-nearest-even
  return (short)(u >> 16);
}

// ---- pre-pass 1: LW2 [64][36864] f32 -> LW2T bf16 [36864][64] ------------
__global__ void k_transpose(const float* __restrict__ lw2, short* __restrict__ lw2t) {
  __shared__ float tile[64][65];
  int n0 = blockIdx.x * 64;
  int t = threadIdx.x;
#pragma unroll
  for (int k = 0; k < 16; ++k) {
    int idx = k * 256 + t;
    int c = idx >> 6, j = idx & 63;
    tile[c][j] = lw2[(size_t)c * 36864 + n0 + j];
  }
  __syncthreads();
#pragma unroll
  for (int k = 0; k < 16; ++k) {
    int idx = k * 256 + t;
    int n = idx >> 6, c = idx & 63;
    lw2t[(size_t)(n0 + n) * 64 + c] = f2bf(tile[c][n]);
  }
}

// ---- pre-pass 2: packed bias matrices ------------------------------------
__global__ void k_bias(const float* __restrict__ bw2, const float* __restrict__ lb2,
                       const float* __restrict__ bb2,
                       short* __restrict__ bb00, short* __restrict__ bb11,
                       short* __restrict__ bb01, short* __restrict__ bb10) {
  int r = blockIdx.x * 256 + threadIdx.x;
  if (r < 1024) {
    int uv = r;
    for (int k = 0; k < 64; ++k) bb00[uv * 96 + k] = f2bf(bw2[k * 1280 + uv]);
    for (int w = 0; w < 16; ++w) bb00[uv * 96 + 64 + w] = f2bf(lb2[w * 1024 + uv]);
    bb00[uv * 96 + 80] = f2bf(bb2[uv]);
    for (int k = 81; k < 96; ++k) bb00[uv * 96 + k] = 0;
  } else if (r < 1280) {
    int uv = r - 1024;
    for (int k = 0; k < 64; ++k) bb11[uv * 96 + k] = f2bf(bw2[k * 1280 + 1024 + uv]);
    for (int w = 0; w < 16; ++w) bb11[uv * 96 + 64 + w] = f2bf(lb2[16384 + w * 256 + uv]);
    bb11[uv * 96 + 80] = f2bf(bb2[1024 + uv]);
    for (int k = 81; k < 96; ++k) bb11[uv * 96 + k] = 0;
  } else if (r < 1792) {
    int uv = r - 1280;
    for (int w = 0; w < 16; ++w) bb01[uv * 32 + w] = f2bf(lb2[20480 + w * 512 + uv]);
    for (int k = 16; k < 32; ++k) bb01[uv * 32 + k] = 0;
  } else if (r < 2304) {
    int uv = r - 1792;
    for (int w = 0; w < 16; ++w) bb10[uv * 32 + w] = f2bf(lb2[28672 + w * 512 + uv]);
    for (int k = 16; k < 32; ++k) bb10[uv * 32 + k] = 0;
  }
}

// ---- pre-pass 3: per-sample h, h2, x0, x1 --------------------------------
__global__ void k_samples(const float* __restrict__ feat, const float* __restrict__ ne,
                          const float* __restrict__ W0, const float* __restrict__ W1,
                          const float* __restrict__ lw1, const float* __restrict__ lb1,
                          const float* __restrict__ bw1, const float* __restrict__ bb1,
                          float* __restrict__ H, float* __restrict__ H2,
                          float* __restrict__ X0, float* __restrict__ X1) {
  int b = blockIdx.x;
  int t = threadIdx.x;               // 192 threads
  __shared__ float sne[128];
  __shared__ float sf[320];
  if (t < 128) sne[t] = ne[(size_t)b * 128 + t];
  for (int i = t; i < 320; i += 192) sf[i] = feat[(size_t)b * 320 + i];
  __syncthreads();
  if (t < 64) {
    float a = lb1[t];
    for (int k = 0; k < 128; ++k) a += sne[k] * lw1[k * 64 + t];
    H[(size_t)b * 64 + t] = a / (1.0f + expf(-a));
  } else if (t < 128) {
    int c = t - 64;
    float a = bb1[c];
    for (int k = 0; k < 128; ++k) a += sne[k] * bw1[k * 64 + c];
    H2[(size_t)b * 64 + c] = a / (1.0f + expf(-a));
  } else if (t < 144) {
    int v = t - 128;
    float a = 0.0f;
    for (int u = 0; u < 128; ++u) a += sf[u] * W0[u * 16 + v];
    X0[(size_t)b * 16 + v] = a * 0.08838834764831845f;  // 1/sqrt(128)
  } else {
    int idx = t - 144, v = idx / 3, j = idx % 3;        // idx < 48
    float a = 0.0f;
    for (int u = 0; u < 64; ++u) a += sf[128 + u * 3 + j] * W1[u * 16 + v];
    X1[(size_t)b * 48 + v * 3 + j] = a * 0.125f;        // 1/sqrt(64)
  }
}

// ---- main kernel ----------------------------------------------------------
// Phase A helper: 2 sample-group Q-planes (stride 16384 shorts), NBIAS bias.
template <int N, int NOFF, int NSTR, int NBIAS, int BBW>
static __device__ __forceinline__ void mmA2(
    const short* __restrict__ LW2T, const short* __restrict__ BB,
    const short* __restrict__ sQp, const short* __restrict__ sAbp,
    int uvbase, int col, int q, f32x4 (&acc)[2][N]) {
  const short* lw = LW2T + (size_t)(NOFF + uvbase + col) * 64;
  const int aoff = col * 32 + q * 8;   // within [col][q][e]; kk stride = 512
  auto bptr = [&](int kk, int i) -> const bf16x8* {
    return (const bf16x8*)(lw + ((size_t)(kk >> 1) * NSTR + i * 16) * 64 +
                           ((kk & 1) * 32 + q * 8));
  };
  bf16x8 Ba[N], Bb[N];
#pragma unroll
  for (int i = 0; i < N; ++i) Ba[i] = *bptr(0, i);
#pragma unroll
  for (int i = 0; i < N; ++i) Bb[i] = *bptr(1, i);
#pragma unroll
  for (int k2 = 0; k2 < 16; ++k2) {
    const int kA = 2 * k2, kB = 2 * k2 + 1;
    {
      const bf16x8 A0 = *(const bf16x8*)(sQp + kA * 512 + aoff);
      const bf16x8 A1 = *(const bf16x8*)(sQp + 16384 + kA * 512 + aoff);
#pragma unroll
      for (int i = 0; i < N; ++i) {
        acc[0][i] = __builtin_amdgcn_mfma_f32_16x16x32_bf16(A0, Ba[i], acc[0][i], 0, 0, 0);
        acc[1][i] = __builtin_amdgcn_mfma_f32_16x16x32_bf16(A1, Ba[i], acc[1][i], 0, 0, 0);
      }
    }
    if (kA + 2 < 32) {
#pragma unroll
      for (int i = 0; i < N; ++i) Ba[i] = *bptr(kA + 2, i);
    }
    {
      const bf16x8 A0 = *(const bf16x8*)(sQp + kB * 512 + aoff);
      const bf16x8 A1 = *(const bf16x8*)(sQp + 16384 + kB * 512 + aoff);
#pragma unroll
      for (int i = 0; i < N; ++i) {
        acc[0][i] = __builtin_amdgcn_mfma_f32_16x16x32_bf16(A0, Bb[i], acc[0][i], 0, 0, 0);
        acc[1][i] = __builtin_amdgcn_mfma_f32_16x16x32_bf16(A1, Bb[i], acc[1][i], 0, 0, 0);
      }
    }
    if (kB + 2 < 32) {
#pragma unroll
      for (int i = 0; i < N; ++i) Bb[i] = *bptr(kB + 2, i);
    }
  }
#pragma unroll
  for (int kk = 0; kk < NBIAS; ++kk) {
    const bf16x8 Ab0 = *(const bf16x8*)(sAbp + kk * 512 + aoff);
    const bf16x8 Ab1 = *(const bf16x8*)(sAbp + NBIAS * 512 + kk * 512 + aoff);
#pragma unroll
    for (int i = 0; i < N; ++i) {
      const bf16x8 B = *(const bf16x8*)(BB + (uvbase + i * 16 + col) * BBW + kk * 32 + q * 8);
      acc[0][i] = __builtin_amdgcn_mfma_f32_16x16x32_bf16(Ab0, B, acc[0][i], 0, 0, 0);
      acc[1][i] = __builtin_amdgcn_mfma_f32_16x16x32_bf16(Ab1, B, acc[1][i], 0, 0, 0);
    }
  }
}

// Phase B helper: NP Q-planes share each B load; 1 bias MFMA per plane.
template <int NP, int N, int NOFF, int NSTR, int BBW>
static __device__ __forceinline__ void mmBnp(
    const short* __restrict__ LW2T, const short* __restrict__ BB,
    const short* __restrict__ sQp, const short* __restrict__ sA1p,
    int uvbase, int col, int q, f32x4 (&acc)[NP][N]) {
  const short* lw = LW2T + (size_t)(NOFF + uvbase + col) * 64;
  const int aoff = col * 32 + q * 8;
  auto bptr = [&](int kk, int i) -> const bf16x8* {
    return (const bf16x8*)(lw + ((size_t)(kk >> 1) * NSTR + i * 16) * 64 +
                           ((kk & 1) * 32 + q * 8));
  };
  bf16x8 Ba[N], Bb[N];
#pragma unroll
  for (int i = 0; i < N; ++i) Ba[i] = *bptr(0, i);
#pragma unroll
  for (int i = 0; i < N; ++i) Bb[i] = *bptr(1, i);
#pragma unroll
  for (int k2 = 0; k2 < 16; ++k2) {
    const int kA = 2 * k2, kB = 2 * k2 + 1;
    {
      bf16x8 A[NP];
#pragma unroll
      for (int p = 0; p < NP; ++p) A[p] = *(const bf16x8*)(sQp + p * 16384 + kA * 512 + aoff);
#pragma unroll
      for (int i = 0; i < N; ++i)
#pragma unroll
        for (int p = 0; p < NP; ++p)
          acc[p][i] = __builtin_amdgcn_mfma_f32_16x16x32_bf16(A[p], Ba[i], acc[p][i], 0, 0, 0);
    }
    if (kA + 2 < 32) {
#pragma unroll
      for (int i = 0; i < N; ++i) Ba[i] = *bptr(kA + 2, i);
    }
    {
      bf16x8 A[NP];
#pragma unroll
      for (int p = 0; p < NP; ++p) A[p] = *(const bf16x8*)(sQp + p * 16384 + kB * 512 + aoff);
#pragma unroll
      for (int i = 0; i < N; ++i)
#pragma unroll
        for (int p = 0; p < NP; ++p)
          acc[p][i] = __builtin_amdgcn_mfma_f32_16x16x32_bf16(A[p], Bb[i], acc[p][i], 0, 0, 0);
    }
    if (kB + 2 < 32) {
#pragma unroll
      for (int i = 0; i < N; ++i) Bb[i] = *bptr(kB + 2, i);
    }
  }
  // bias: k < 16 only; same B row for all planes
#pragma unroll
  for (int i = 0; i < N; ++i) {
    const bf16x8 B = *(const bf16x8*)(BB + (uvbase + i * 16 + col) * BBW + q * 8);
#pragma unroll
    for (int p = 0; p < NP; ++p) {
      const bf16x8 Ap = *(const bf16x8*)(sA1p + p * 512 + aoff);
      acc[p][i] = __builtin_amdgcn_mfma_f32_16x16x32_bf16(Ap, B, acc[p][i], 0, 0, 0);
    }
  }
}

__global__ __launch_bounds__(512, 1) void k_main(
    const short* __restrict__ LW2T,
    const short* __restrict__ BB00, const short* __restrict__ BB11,
    const short* __restrict__ BB01, const short* __restrict__ BB10,
    const float* __restrict__ H, const float* __restrict__ H2,
    const float* __restrict__ X0, const float* __restrict__ X1,
    float* __restrict__ out) {
  constexpr float S00 = 0.0625f;                  // 1/16
  constexpr float S3 = 0.036084391824351614f;     // (1/sqrt(3))/16

  // blockIdx = (s&7) + 8*(h + 2*(s>>3)): tile s in [0,128), half h in {0,1}.
  // Both halves of a tile land on the same XCD (idx%8 = s%8).
  int idx = blockIdx.x;
  int xcd = idx & 7;
  int rest = idx >> 3;
  int h = rest & 1;
  int s = xcd + 8 * (rest >> 1);     // 0..127
  int b0 = s << 5;                   // 32 samples per tile
  int t = threadIdx.x;               // 512 threads = 8 waves
  int lane = t & 63, wave = t >> 6;
  int col = lane & 15, q = lane >> 4;

  __shared__ float sH[32][66];
  __shared__ float sX0[32][17];
  __shared__ float sX1[32][51];
  __shared__ short sQ[4][32][16][4][8];   // 128 KB, planes of 16384 shorts
  __shared__ short sAb[2][3][16][4][8];   // phase-A bias planes per group
  __shared__ short sA1[3][2][16][4][8];   // phase-B bias planes [j][g]

  for (int i = t; i < 2048; i += 512)
    sH[i >> 6][i & 63] = H[(size_t)(b0 + (i >> 6)) * 64 + (i & 63)];
  sX0[t >> 4][t & 15] = X0[(size_t)(b0 + (t >> 4)) * 16 + (t & 15)];
  for (int i = t; i < 1536; i += 512)
    sX1[i / 48][i % 48] = X1[(size_t)(b0 + i / 48) * 48 + (i % 48)];
  __syncthreads();

  // ===== build phase-A Q planes (g=0,1), sAb, sA1 =========================
  for (int i = t; i < 16384; i += 512) {
    int p = i >> 13, rem = i & 8191;
    int kk = rem >> 8, cc = (rem >> 4) & 15, qq = (rem >> 2) & 3, e2 = (rem & 3) << 1;
    int k = kk * 32 + qq * 8 + e2;
    int w = k >> 6, c = k & 63;
    float xw = sX0[p * 16 + cc][w];
    unsigned lo = (unsigned short)f2bf(sH[p * 16 + cc][c] * xw);
    unsigned hi = (unsigned short)f2bf(sH[p * 16 + cc][c + 1] * xw);
    *(unsigned*)&sQ[p][kk][cc][qq][e2] = lo | (hi << 16);
  }
  for (int i = t; i < 3072; i += 512) {   // sAb
    int g = (i >= 1536), rem = i - (g ? 1536 : 0);
    int kk = rem >> 9, r2 = rem & 511;
    int cc = r2 >> 5, qq = (r2 >> 3) & 3, e = r2 & 7;
    int k = kk * 32 + qq * 8 + e;
    float v = 0.0f;
    if (k < 64) v = H2[(size_t)(b0 + g * 16 + cc) * 64 + k];
    else if (k < 80) v = sX0[g * 16 + cc][k - 64];
    else if (k == 80) v = 1.0f;
    sAb[g][kk][cc][qq][e] = f2bf(v);
  }
  for (int i = t; i < 3072; i += 512) {   // sA1 (all 3 j)
    int j = i >> 10, rem = i & 1023;
    int g = rem >> 9, r2 = rem & 511;
    int cc = r2 >> 5, qq = (r2 >> 3) & 3, e = r2 & 7;
    int k = qq * 8 + e;
    sA1[j][g][cc][qq][e] = (k < 16) ? f2bf(sX1[g * 16 + cc][k * 3 + j]) : (short)0;
  }
  __syncthreads();

  // ===== phase A: path00 (uv-half 512, wave owns 64) ======================
  {
    int uvbase = h * 512 + wave * 64;
    f32x4 acc[2][4] = {};
    mmA2<4, 0, 1024, 3, 96>(LW2T, BB00, &sQ[0][0][0][0][0], &sAb[0][0][0][0][0],
                            uvbase, col, q, acc);
#pragma unroll
    for (int g = 0; g < 2; ++g)
#pragma unroll
      for (int i = 0; i < 4; ++i)
#pragma unroll
        for (int ii = 0; ii < 4; ++ii) {
          size_t ob = (size_t)(b0 + g * 16 + q * 4 + ii) * 6400;
          int uv = uvbase + i * 16 + col;
          out[ob + (uv >> 5) * 80 + (uv & 31)] = acc[g][i][ii] * S00;
        }
  }
  // path11 (uv-half 128, wave owns 16)
  {
    int uvbase = h * 128 + wave * 16;
    f32x4 acc[2][1] = {};
    mmA2<1, 16384, 256, 3, 96>(LW2T, BB11, &sQ[0][0][0][0][0], &sAb[0][0][0][0][0],
                               uvbase, col, q, acc);
#pragma unroll
    for (int g = 0; g < 2; ++g)
#pragma unroll
      for (int ii = 0; ii < 4; ++ii) {
        size_t ob = (size_t)(b0 + g * 16 + q * 4 + ii) * 6400;
        int uv = uvbase + col;
        float val = acc[g][0][ii] * S3;
        int u = uv >> 4, v = uv & 15;
        float* p = out + ob + (size_t)(32 + 3 * u) * 80 + (32 + 3 * v);
        p[0] = val;   p[1] = 0.f;   p[2] = 0.f;
        p[80] = 0.f;  p[81] = val;  p[82] = 0.f;
        p[160] = 0.f; p[161] = 0.f; p[162] = val;
      }
  }

  // ===== phase B pass 1: planes (j,g) = (0,0),(0,1),(1,0),(1,1) ===========
  __syncthreads();
  for (int i = t; i < 32768; i += 512) {
    int p = i >> 13, rem = i & 8191;
    int j = p >> 1, g = p & 1;
    int kk = rem >> 8, cc = (rem >> 4) & 15, qq = (rem >> 2) & 3, e2 = (rem & 3) << 1;
    int k = kk * 32 + qq * 8 + e2;
    int w = k >> 6, c = k & 63;
    float xw = sX1[g * 16 + cc][w * 3 + j];
    unsigned lo = (unsigned short)f2bf(sH[g * 16 + cc][c] * xw);
    unsigned hi = (unsigned short)f2bf(sH[g * 16 + cc][c + 1] * xw);
    *(unsigned*)&sQ[p][kk][cc][qq][e2] = lo | (hi << 16);
  }
  __syncthreads();
  {
    int uvbase = h * 256 + wave * 32;
    {
      f32x4 acc[4][2] = {};
      mmBnp<4, 2, 20480, 512, 32>(LW2T, BB01, &sQ[0][0][0][0][0],
                                  &sA1[0][0][0][0][0], uvbase, col, q, acc);
#pragma unroll
      for (int p = 0; p < 4; ++p)
#pragma unroll
        for (int i = 0; i < 2; ++i)
#pragma unroll
          for (int ii = 0; ii < 4; ++ii) {
            int j = p >> 1, g = p & 1;
            size_t ob = (size_t)(b0 + g * 16 + q * 4 + ii) * 6400;
            int uv = uvbase + i * 16 + col;
            out[ob + (uv >> 4) * 80 + 32 + 3 * (uv & 15) + j] = acc[p][i][ii] * S3;
          }
    }
    {
      f32x4 acc[4][2] = {};
      mmBnp<4, 2, 28672, 512, 32>(LW2T, BB10, &sQ[0][0][0][0][0],
                                  &sA1[0][0][0][0][0], uvbase, col, q, acc);
#pragma unroll
      for (int p = 0; p < 4; ++p)
#pragma unroll
        for (int i = 0; i < 2; ++i)
#pragma unroll
          for (int ii = 0; ii < 4; ++ii) {
            int j = p >> 1, g = p & 1;
            size_t ob = (size_t)(b0 + g * 16 + q * 4 + ii) * 6400;
            int uv = uvbase + i * 16 + col;
            out[ob + (size_t)(32 + 3 * (uv >> 5) + j) * 80 + (uv & 31)] = acc[p][i][ii] * S3;
          }
    }
  }

  // ===== phase B pass 2: planes g = 0,1 at j = 2 ==========================
  __syncthreads();
  for (int i = t; i < 16384; i += 512) {
    int g = i >> 13, rem = i & 8191;
    int kk = rem >> 8, cc = (rem >> 4) & 15, qq = (rem >> 2) & 3, e2 = (rem & 3) << 1;
    int k = kk * 32 + qq * 8 + e2;
    int w = k >> 6, c = k & 63;
    float xw = sX1[g * 16 + cc][w * 3 + 2];
    unsigned lo = (unsigned short)f2bf(sH[g * 16 + cc][c] * xw);
    unsigned hi = (unsigned short)f2bf(sH[g * 16 + cc][c + 1] * xw);
    *(unsigned*)&sQ[g][kk][cc][qq][e2] = lo | (hi << 16);
  }
  __syncthreads();
  {
    int uvbase = h * 256 + wave * 32;
    {
      f32x4 acc[2][2] = {};
      mmBnp<2, 2, 20480, 512, 32>(LW2T, BB01, &sQ[0][0][0][0][0],
                                  &sA1[2][0][0][0][0], uvbase, col, q, acc);
#pragma unroll
      for (int g = 0; g < 2; ++g)
#pragma unroll
        for (int i = 0; i < 2; ++i)
#pragma unroll
          for (int ii = 0; ii < 4; ++ii) {
            size_t ob = (size_t)(b0 + g * 16 + q * 4 + ii) * 6400;
            int uv = uvbase + i * 16 + col;
            out[ob + (uv >> 4) * 80 + 32 + 3 * (uv & 15) + 2] = acc[g][i][ii] * S3;
          }
    }
    {
      f32x4 acc[2][2] = {};
      mmBnp<2, 2, 28672, 512, 32>(LW2T, BB10, &sQ[0][0][0][0][0],
                                  &sA1[2][0][0][0][0], uvbase, col, q, acc);
#pragma unroll
      for (int g = 0; g < 2; ++g)
#pragma unroll
        for (int i = 0; i < 2; ++i)
#pragma unroll
          for (int ii = 0; ii < 4; ++ii) {
            size_t ob = (size_t)(b0 + g * 16 + q * 4 + ii) * 6400;
            int uv = uvbase + i * 16 + col;
            out[ob + (size_t)(32 + 3 * (uv >> 5) + 2) * 80 + (uv & 31)] = acc[g][i][ii] * S3;
          }
    }
  }
}

// ---------------------------------------------------------------------------
extern "C" void kernel_launch(void* const* d_in, const int* in_sizes, int n_in,
                              void* d_out, int out_size, void* d_ws, size_t ws_size,
                              hipStream_t stream) {
  const float* feat = (const float*)d_in[0];
  const float* ne   = (const float*)d_in[1];
  const float* W0   = (const float*)d_in[2];
  const float* W1   = (const float*)d_in[3];
  const float* lw1  = (const float*)d_in[4];
  const float* lb1  = (const float*)d_in[5];
  const float* lw2  = (const float*)d_in[6];
  const float* lb2  = (const float*)d_in[7];
  const float* bw1  = (const float*)d_in[8];
  const float* bb1  = (const float*)d_in[9];
  const float* bw2  = (const float*)d_in[10];
  const float* bb2  = (const float*)d_in[11];

  char* ws = (char*)d_ws;
  short* LW2T = (short*)ws; ws += (size_t)36864 * 64 * 2;   // 4.72 MB
  short* BB00 = (short*)ws; ws += (size_t)1024 * 96 * 2;
  short* BB11 = (short*)ws; ws += (size_t)256 * 96 * 2;
  short* BB01 = (short*)ws; ws += (size_t)512 * 32 * 2;
  short* BB10 = (short*)ws; ws += (size_t)512 * 32 * 2;
  float* H  = (float*)ws;   ws += (size_t)4096 * 64 * 4;
  float* H2 = (float*)ws;   ws += (size_t)4096 * 64 * 4;
  float* X0 = (float*)ws;   ws += (size_t)4096 * 16 * 4;
  float* X1 = (float*)ws;   ws += (size_t)4096 * 48 * 4;
  (void)ws_size; (void)in_sizes; (void)n_in; (void)out_size;

  hipLaunchKernelGGL(k_transpose, dim3(576), dim3(256), 0, stream, lw2, LW2T);
  hipLaunchKernelGGL(k_bias, dim3(9), dim3(256), 0, stream, bw2, lb2, bb2,
                     BB00, BB11, BB01, BB10);
  hipLaunchKernelGGL(k_samples, dim3(4096), dim3(192), 0, stream,
                     feat, ne, W0, W1, lw1, lb1, bw1, bb1, H, H2, X0, X1);
  hipLaunchKernelGGL(k_main, dim3(256), dim3(512), 0, stream,
                     LW2T, BB00, BB11, BB01, BB10, H, H2, X0, X1, (float*)d_out);
}

// Round 9
// 171.726 us; speedup vs baseline: 5.0151x; 1.0388x over previous
//
#include <hip/hip_runtime.h>
#include <hip/hip_bf16.h>
#include <math.h>

// ---------------------------------------------------------------------------
// Expansion kernel.  Q-form fusion: out[b,uv] = sum_k Q[b,k]*LW2T[n(uv),k]
// Round 9: round-8 structure + (1) XCD<->uv-half affinity: blockIdx slot =
// (s&3)+4h so XCDs 0-3 only ever read B-half 0 (2.36 MB, fits 4 MiB L2) and
// XCDs 4-7 read half 1.  Round-8 counters showed B (4.72 MB) thrashing the
// XCD L2: FETCH 21->51 MB and WRITE 102->163 MB (dirty partial out lines
// evicted by the B stream, then refetched).  The h-split row boundaries
// (bytes 5120 / 17920 per sample) are 128B-aligned -> halves share zero out
// lines, so cross-XCD placement is safe.  (2) depth-4 B register pipeline
// (was depth-2): 16 loads in flight per wave hides ~200cy L2 latency.
// ---------------------------------------------------------------------------

typedef short bf16x8 __attribute__((ext_vector_type(8)));
typedef float f32x4 __attribute__((ext_vector_type(4)));

static __device__ __forceinline__ short f2bf(float f) {
  unsigned u = __builtin_bit_cast(unsigned, f);
  u = u + 0x7fffu + ((u >> 16) & 1u);   // round-to-nearest-even
  return (short)(u >> 16);
}

// ---- pre-pass 1: LW2 [64][36864] f32 -> LW2T bf16 [36864][64] ------------
__global__ void k_transpose(const float* __restrict__ lw2, short* __restrict__ lw2t) {
  __shared__ float tile[64][65];
  int n0 = blockIdx.x * 64;
  int t = threadIdx.x;
#pragma unroll
  for (int k = 0; k < 16; ++k) {
    int idx = k * 256 + t;
    int c = idx >> 6, j = idx & 63;
    tile[c][j] = lw2[(size_t)c * 36864 + n0 + j];
  }
  __syncthreads();
#pragma unroll
  for (int k = 0; k < 16; ++k) {
    int idx = k * 256 + t;
    int n = idx >> 6, c = idx & 63;
    lw2t[(size_t)(n0 + n) * 64 + c] = f2bf(tile[c][n]);
  }
}

// ---- pre-pass 2: packed bias matrices ------------------------------------
__global__ void k_bias(const float* __restrict__ bw2, const float* __restrict__ lb2,
                       const float* __restrict__ bb2,
                       short* __restrict__ bb00, short* __restrict__ bb11,
                       short* __restrict__ bb01, short* __restrict__ bb10) {
  int r = blockIdx.x * 256 + threadIdx.x;
  if (r < 1024) {
    int uv = r;
    for (int k = 0; k < 64; ++k) bb00[uv * 96 + k] = f2bf(bw2[k * 1280 + uv]);
    for (int w = 0; w < 16; ++w) bb00[uv * 96 + 64 + w] = f2bf(lb2[w * 1024 + uv]);
    bb00[uv * 96 + 80] = f2bf(bb2[uv]);
    for (int k = 81; k < 96; ++k) bb00[uv * 96 + k] = 0;
  } else if (r < 1280) {
    int uv = r - 1024;
    for (int k = 0; k < 64; ++k) bb11[uv * 96 + k] = f2bf(bw2[k * 1280 + 1024 + uv]);
    for (int w = 0; w < 16; ++w) bb11[uv * 96 + 64 + w] = f2bf(lb2[16384 + w * 256 + uv]);
    bb11[uv * 96 + 80] = f2bf(bb2[1024 + uv]);
    for (int k = 81; k < 96; ++k) bb11[uv * 96 + k] = 0;
  } else if (r < 1792) {
    int uv = r - 1280;
    for (int w = 0; w < 16; ++w) bb01[uv * 32 + w] = f2bf(lb2[20480 + w * 512 + uv]);
    for (int k = 16; k < 32; ++k) bb01[uv * 32 + k] = 0;
  } else if (r < 2304) {
    int uv = r - 1792;
    for (int w = 0; w < 16; ++w) bb10[uv * 32 + w] = f2bf(lb2[28672 + w * 512 + uv]);
    for (int k = 16; k < 32; ++k) bb10[uv * 32 + k] = 0;
  }
}

// ---- pre-pass 3: per-sample h, h2, x0, x1 --------------------------------
__global__ void k_samples(const float* __restrict__ feat, const float* __restrict__ ne,
                          const float* __restrict__ W0, const float* __restrict__ W1,
                          const float* __restrict__ lw1, const float* __restrict__ lb1,
                          const float* __restrict__ bw1, const float* __restrict__ bb1,
                          float* __restrict__ H, float* __restrict__ H2,
                          float* __restrict__ X0, float* __restrict__ X1) {
  int b = blockIdx.x;
  int t = threadIdx.x;               // 192 threads
  __shared__ float sne[128];
  __shared__ float sf[320];
  if (t < 128) sne[t] = ne[(size_t)b * 128 + t];
  for (int i = t; i < 320; i += 192) sf[i] = feat[(size_t)b * 320 + i];
  __syncthreads();
  if (t < 64) {
    float a = lb1[t];
    for (int k = 0; k < 128; ++k) a += sne[k] * lw1[k * 64 + t];
    H[(size_t)b * 64 + t] = a / (1.0f + expf(-a));
  } else if (t < 128) {
    int c = t - 64;
    float a = bb1[c];
    for (int k = 0; k < 128; ++k) a += sne[k] * bw1[k * 64 + c];
    H2[(size_t)b * 64 + c] = a / (1.0f + expf(-a));
  } else if (t < 144) {
    int v = t - 128;
    float a = 0.0f;
    for (int u = 0; u < 128; ++u) a += sf[u] * W0[u * 16 + v];
    X0[(size_t)b * 16 + v] = a * 0.08838834764831845f;  // 1/sqrt(128)
  } else {
    int idx = t - 144, v = idx / 3, j = idx % 3;        // idx < 48
    float a = 0.0f;
    for (int u = 0; u < 64; ++u) a += sf[128 + u * 3 + j] * W1[u * 16 + v];
    X1[(size_t)b * 48 + v * 3 + j] = a * 0.125f;        // 1/sqrt(64)
  }
}

// ---- main kernel ----------------------------------------------------------
// Phase A helper: 2 sample-group Q-planes (stride 16384 shorts), NBIAS bias.
// Depth-4 B register pipeline; kk loop fully unrolled -> static buffer idx.
template <int N, int NOFF, int NSTR, int NBIAS, int BBW>
static __device__ __forceinline__ void mmA2(
    const short* __restrict__ LW2T, const short* __restrict__ BB,
    const short* __restrict__ sQp, const short* __restrict__ sAbp,
    int uvbase, int col, int q, f32x4 (&acc)[2][N]) {
  const short* lw = LW2T + (size_t)(NOFF + uvbase + col) * 64;
  const int aoff = col * 32 + q * 8;   // kk stride = 512 shorts
  auto bptr = [&](int kk, int i) -> const bf16x8* {
    return (const bf16x8*)(lw + ((size_t)(kk >> 1) * NSTR + i * 16) * 64 +
                           ((kk & 1) * 32 + q * 8));
  };
  bf16x8 B[4][N];
#pragma unroll
  for (int d = 0; d < 4; ++d)
#pragma unroll
    for (int i = 0; i < N; ++i) B[d][i] = *bptr(d, i);
#pragma unroll
  for (int kk = 0; kk < 32; ++kk) {
    const int d = kk & 3;
    const bf16x8 A0 = *(const bf16x8*)(sQp + kk * 512 + aoff);
    const bf16x8 A1 = *(const bf16x8*)(sQp + 16384 + kk * 512 + aoff);
#pragma unroll
    for (int i = 0; i < N; ++i) {
      acc[0][i] = __builtin_amdgcn_mfma_f32_16x16x32_bf16(A0, B[d][i], acc[0][i], 0, 0, 0);
      acc[1][i] = __builtin_amdgcn_mfma_f32_16x16x32_bf16(A1, B[d][i], acc[1][i], 0, 0, 0);
    }
    if (kk + 4 < 32) {
#pragma unroll
      for (int i = 0; i < N; ++i) B[d][i] = *bptr(kk + 4, i);
    }
  }
#pragma unroll
  for (int kk = 0; kk < NBIAS; ++kk) {
    const bf16x8 Ab0 = *(const bf16x8*)(sAbp + kk * 512 + aoff);
    const bf16x8 Ab1 = *(const bf16x8*)(sAbp + NBIAS * 512 + kk * 512 + aoff);
#pragma unroll
    for (int i = 0; i < N; ++i) {
      const bf16x8 Bx = *(const bf16x8*)(BB + (uvbase + i * 16 + col) * BBW + kk * 32 + q * 8);
      acc[0][i] = __builtin_amdgcn_mfma_f32_16x16x32_bf16(Ab0, Bx, acc[0][i], 0, 0, 0);
      acc[1][i] = __builtin_amdgcn_mfma_f32_16x16x32_bf16(Ab1, Bx, acc[1][i], 0, 0, 0);
    }
  }
}

// Phase B helper: NP Q-planes share each B load; depth-4 pipeline.
template <int NP, int N, int NOFF, int NSTR, int BBW>
static __device__ __forceinline__ void mmBnp(
    const short* __restrict__ LW2T, const short* __restrict__ BB,
    const short* __restrict__ sQp, const short* __restrict__ sA1p,
    int uvbase, int col, int q, f32x4 (&acc)[NP][N]) {
  const short* lw = LW2T + (size_t)(NOFF + uvbase + col) * 64;
  const int aoff = col * 32 + q * 8;
  auto bptr = [&](int kk, int i) -> const bf16x8* {
    return (const bf16x8*)(lw + ((size_t)(kk >> 1) * NSTR + i * 16) * 64 +
                           ((kk & 1) * 32 + q * 8));
  };
  bf16x8 B[4][N];
#pragma unroll
  for (int d = 0; d < 4; ++d)
#pragma unroll
    for (int i = 0; i < N; ++i) B[d][i] = *bptr(d, i);
#pragma unroll
  for (int kk = 0; kk < 32; ++kk) {
    const int d = kk & 3;
    bf16x8 A[NP];
#pragma unroll
    for (int p = 0; p < NP; ++p)
      A[p] = *(const bf16x8*)(sQp + p * 16384 + kk * 512 + aoff);
#pragma unroll
    for (int i = 0; i < N; ++i)
#pragma unroll
      for (int p = 0; p < NP; ++p)
        acc[p][i] = __builtin_amdgcn_mfma_f32_16x16x32_bf16(A[p], B[d][i], acc[p][i], 0, 0, 0);
    if (kk + 4 < 32) {
#pragma unroll
      for (int i = 0; i < N; ++i) B[d][i] = *bptr(kk + 4, i);
    }
  }
  // bias: k < 16 only; same B row for all planes
#pragma unroll
  for (int i = 0; i < N; ++i) {
    const bf16x8 Bx = *(const bf16x8*)(BB + (uvbase + i * 16 + col) * BBW + q * 8);
#pragma unroll
    for (int p = 0; p < NP; ++p) {
      const bf16x8 Ap = *(const bf16x8*)(sA1p + p * 512 + aoff);
      acc[p][i] = __builtin_amdgcn_mfma_f32_16x16x32_bf16(Ap, Bx, acc[p][i], 0, 0, 0);
    }
  }
}

__global__ __launch_bounds__(512, 1) void k_main(
    const short* __restrict__ LW2T,
    const short* __restrict__ BB00, const short* __restrict__ BB11,
    const short* __restrict__ BB01, const short* __restrict__ BB10,
    const float* __restrict__ H, const float* __restrict__ H2,
    const float* __restrict__ X0, const float* __restrict__ X1,
    float* __restrict__ out) {
  constexpr float S00 = 0.0625f;                  // 1/16
  constexpr float S3 = 0.036084391824351614f;     // (1/sqrt(3))/16

  // blockIdx = slot + 8*seq, slot = (s&3) + 4*h  ->  XCD = slot:
  // XCDs 0..3 only read B-half 0, XCDs 4..7 only half 1 (2.36 MB each,
  // L2-resident).  h-split row boundaries are 128B-aligned -> no out-line
  // sharing across XCDs.
  int idx = blockIdx.x;
  int slot = idx & 7;
  int h = slot >> 2;
  int s = (slot & 3) + 4 * (idx >> 3);   // 0..127
  int b0 = s << 5;                        // 32 samples per tile
  int t = threadIdx.x;                    // 512 threads = 8 waves
  int lane = t & 63, wave = t >> 6;
  int col = lane & 15, q = lane >> 4;

  __shared__ float sH[32][66];
  __shared__ float sX0[32][17];
  __shared__ float sX1[32][51];
  __shared__ short sQ[4][32][16][4][8];   // 128 KB, planes of 16384 shorts
  __shared__ short sAb[2][3][16][4][8];   // phase-A bias planes per group
  __shared__ short sA1[3][2][16][4][8];   // phase-B bias planes [j][g]

  for (int i = t; i < 2048; i += 512)
    sH[i >> 6][i & 63] = H[(size_t)(b0 + (i >> 6)) * 64 + (i & 63)];
  sX0[t >> 4][t & 15] = X0[(size_t)(b0 + (t >> 4)) * 16 + (t & 15)];
  for (int i = t; i < 1536; i += 512)
    sX1[i / 48][i % 48] = X1[(size_t)(b0 + i / 48) * 48 + (i % 48)];
  __syncthreads();

  // ===== build phase-A Q planes (g=0,1), sAb, sA1 =========================
  for (int i = t; i < 16384; i += 512) {
    int p = i >> 13, rem = i & 8191;
    int kk = rem >> 8, cc = (rem >> 4) & 15, qq = (rem >> 2) & 3, e2 = (rem & 3) << 1;
    int k = kk * 32 + qq * 8 + e2;
    int w = k >> 6, c = k & 63;
    float xw = sX0[p * 16 + cc][w];
    unsigned lo = (unsigned short)f2bf(sH[p * 16 + cc][c] * xw);
    unsigned hi = (unsigned short)f2bf(sH[p * 16 + cc][c + 1] * xw);
    *(unsigned*)&sQ[p][kk][cc][qq][e2] = lo | (hi << 16);
  }
  for (int i = t; i < 3072; i += 512) {   // sAb
    int g = (i >= 1536), rem = i - (g ? 1536 : 0);
    int kk = rem >> 9, r2 = rem & 511;
    int cc = r2 >> 5, qq = (r2 >> 3) & 3, e = r2 & 7;
    int k = kk * 32 + qq * 8 + e;
    float v = 0.0f;
    if (k < 64) v = H2[(size_t)(b0 + g * 16 + cc) * 64 + k];
    else if (k < 80) v = sX0[g * 16 + cc][k - 64];
    else if (k == 80) v = 1.0f;
    sAb[g][kk][cc][qq][e] = f2bf(v);
  }
  for (int i = t; i < 3072; i += 512) {   // sA1 (all 3 j)
    int j = i >> 10, rem = i & 1023;
    int g = rem >> 9, r2 = rem & 511;
    int cc = r2 >> 5, qq = (r2 >> 3) & 3, e = r2 & 7;
    int k = qq * 8 + e;
    sA1[j][g][cc][qq][e] = (k < 16) ? f2bf(sX1[g * 16 + cc][k * 3 + j]) : (short)0;
  }
  __syncthreads();

  // ===== phase A: path00 (uv-half 512, wave owns 64) ======================
  {
    int uvbase = h * 512 + wave * 64;
    f32x4 acc[2][4] = {};
    mmA2<4, 0, 1024, 3, 96>(LW2T, BB00, &sQ[0][0][0][0][0], &sAb[0][0][0][0][0],
                            uvbase, col, q, acc);
#pragma unroll
    for (int g = 0; g < 2; ++g)
#pragma unroll
      for (int i = 0; i < 4; ++i)
#pragma unroll
        for (int ii = 0; ii < 4; ++ii) {
          size_t ob = (size_t)(b0 + g * 16 + q * 4 + ii) * 6400;
          int uv = uvbase + i * 16 + col;
          out[ob + (uv >> 5) * 80 + (uv & 31)] = acc[g][i][ii] * S00;
        }
  }
  // path11 (uv-half 128, wave owns 16)
  {
    int uvbase = h * 128 + wave * 16;
    f32x4 acc[2][1] = {};
    mmA2<1, 16384, 256, 3, 96>(LW2T, BB11, &sQ[0][0][0][0][0], &sAb[0][0][0][0][0],
                               uvbase, col, q, acc);
#pragma unroll
    for (int g = 0; g < 2; ++g)
#pragma unroll
      for (int ii = 0; ii < 4; ++ii) {
        size_t ob = (size_t)(b0 + g * 16 + q * 4 + ii) * 6400;
        int uv = uvbase + col;
        float val = acc[g][0][ii] * S3;
        int u = uv >> 4, v = uv & 15;
        float* p = out + ob + (size_t)(32 + 3 * u) * 80 + (32 + 3 * v);
        p[0] = val;   p[1] = 0.f;   p[2] = 0.f;
        p[80] = 0.f;  p[81] = val;  p[82] = 0.f;
        p[160] = 0.f; p[161] = 0.f; p[162] = val;
      }
  }

  // ===== phase B pass 1: planes (j,g) = (0,0),(0,1),(1,0),(1,1) ===========
  __syncthreads();
  for (int i = t; i < 32768; i += 512) {
    int p = i >> 13, rem = i & 8191;
    int j = p >> 1, g = p & 1;
    int kk = rem >> 8, cc = (rem >> 4) & 15, qq = (rem >> 2) & 3, e2 = (rem & 3) << 1;
    int k = kk * 32 + qq * 8 + e2;
    int w = k >> 6, c = k & 63;
    float xw = sX1[g * 16 + cc][w * 3 + j];
    unsigned lo = (unsigned short)f2bf(sH[g * 16 + cc][c] * xw);
    unsigned hi = (unsigned short)f2bf(sH[g * 16 + cc][c + 1] * xw);
    *(unsigned*)&sQ[p][kk][cc][qq][e2] = lo | (hi << 16);
  }
  __syncthreads();
  {
    int uvbase = h * 256 + wave * 32;
    {
      f32x4 acc[4][2] = {};
      mmBnp<4, 2, 20480, 512, 32>(LW2T, BB01, &sQ[0][0][0][0][0],
                                  &sA1[0][0][0][0][0], uvbase, col, q, acc);
#pragma unroll
      for (int p = 0; p < 4; ++p)
#pragma unroll
        for (int i = 0; i < 2; ++i)
#pragma unroll
          for (int ii = 0; ii < 4; ++ii) {
            int j = p >> 1, g = p & 1;
            size_t ob = (size_t)(b0 + g * 16 + q * 4 + ii) * 6400;
            int uv = uvbase + i * 16 + col;
            out[ob + (uv >> 4) * 80 + 32 + 3 * (uv & 15) + j] = acc[p][i][ii] * S3;
          }
    }
    {
      f32x4 acc[4][2] = {};
      mmBnp<4, 2, 28672, 512, 32>(LW2T, BB10, &sQ[0][0][0][0][0],
                                  &sA1[0][0][0][0][0], uvbase, col, q, acc);
#pragma unroll
      for (int p = 0; p < 4; ++p)
#pragma unroll
        for (int i = 0; i < 2; ++i)
#pragma unroll
          for (int ii = 0; ii < 4; ++ii) {
            int j = p >> 1, g = p & 1;
            size_t ob = (size_t)(b0 + g * 16 + q * 4 + ii) * 6400;
            int uv = uvbase + i * 16 + col;
            out[ob + (size_t)(32 + 3 * (uv >> 5) + j) * 80 + (uv & 31)] = acc[p][i][ii] * S3;
          }
    }
  }

  // ===== phase B pass 2: planes g = 0,1 at j = 2 ==========================
  __syncthreads();
  for (int i = t; i < 16384; i += 512) {
    int g = i >> 13, rem = i & 8191;
    int kk = rem >> 8, cc = (rem >> 4) & 15, qq = (rem >> 2) & 3, e2 = (rem & 3) << 1;
    int k = kk * 32 + qq * 8 + e2;
    int w = k >> 6, c = k & 63;
    float xw = sX1[g * 16 + cc][w * 3 + 2];
    unsigned lo = (unsigned short)f2bf(sH[g * 16 + cc][c] * xw);
    unsigned hi = (unsigned short)f2bf(sH[g * 16 + cc][c + 1] * xw);
    *(unsigned*)&sQ[g][kk][cc][qq][e2] = lo | (hi << 16);
  }
  __syncthreads();
  {
    int uvbase = h * 256 + wave * 32;
    {
      f32x4 acc[2][2] = {};
      mmBnp<2, 2, 20480, 512, 32>(LW2T, BB01, &sQ[0][0][0][0][0],
                                  &sA1[2][0][0][0][0], uvbase, col, q, acc);
#pragma unroll
      for (int g = 0; g < 2; ++g)
#pragma unroll
        for (int i = 0; i < 2; ++i)
#pragma unroll
          for (int ii = 0; ii < 4; ++ii) {
            size_t ob = (size_t)(b0 + g * 16 + q * 4 + ii) * 6400;
            int uv = uvbase + i * 16 + col;
            out[ob + (uv >> 4) * 80 + 32 + 3 * (uv & 15) + 2] = acc[g][i][ii] * S3;
          }
    }
    {
      f32x4 acc[2][2] = {};
      mmBnp<2, 2, 28672, 512, 32>(LW2T, BB10, &sQ[0][0][0][0][0],
                                  &sA1[2][0][0][0][0], uvbase, col, q, acc);
#pragma unroll
      for (int g = 0; g < 2; ++g)
#pragma unroll
        for (int i = 0; i < 2; ++i)
#pragma unroll
          for (int ii = 0; ii < 4; ++ii) {
            size_t ob = (size_t)(b0 + g * 16 + q * 4 + ii) * 6400;
            int uv = uvbase + i * 16 + col;
            out[ob + (size_t)(32 + 3 * (uv >> 5) + 2) * 80 + (uv & 31)] = acc[g][i][ii] * S3;
          }
    }
  }
}

// ---------------------------------------------------------------------------
extern "C" void kernel_launch(void* const* d_in, const int* in_sizes, int n_in,
                              void* d_out, int out_size, void* d_ws, size_t ws_size,
                              hipStream_t stream) {
  const float* feat = (const float*)d_in[0];
  const float* ne   = (const float*)d_in[1];
  const float* W0   = (const float*)d_in[2];
  const float* W1   = (const float*)d_in[3];
  const float* lw1  = (const float*)d_in[4];
  const float* lb1  = (const float*)d_in[5];
  const float* lw2  = (const float*)d_in[6];
  const float* lb2  = (const float*)d_in[7];
  const float* bw1  = (const float*)d_in[8];
  const float* bb1  = (const float*)d_in[9];
  const float* bw2  = (const float*)d_in[10];
  const float* bb2  = (const float*)d_in[11];

  char* ws = (char*)d_ws;
  short* LW2T = (short*)ws; ws += (size_t)36864 * 64 * 2;   // 4.72 MB
  short* BB00 = (short*)ws; ws += (size_t)1024 * 96 * 2;
  short* BB11 = (short*)ws; ws += (size_t)256 * 96 * 2;
  short* BB01 = (short*)ws; ws += (size_t)512 * 32 * 2;
  short* BB10 = (short*)ws; ws += (size_t)512 * 32 * 2;
  float* H  = (float*)ws;   ws += (size_t)4096 * 64 * 4;
  float* H2 = (float*)ws;   ws += (size_t)4096 * 64 * 4;
  float* X0 = (float*)ws;   ws += (size_t)4096 * 16 * 4;
  float* X1 = (float*)ws;   ws += (size_t)4096 * 48 * 4;
  (void)ws_size; (void)in_sizes; (void)n_in; (void)out_size;

  hipLaunchKernelGGL(k_transpose, dim3(576), dim3(256), 0, stream, lw2, LW2T);
  hipLaunchKernelGGL(k_bias, dim3(9), dim3(256), 0, stream, bw2, lb2, bb2,
                     BB00, BB11, BB01, BB10);
  hipLaunchKernelGGL(k_samples, dim3(4096), dim3(192), 0, stream,
                     feat, ne, W0, W1, lw1, lb1, bw1, bb1, H, H2, X0, X1);
  hipLaunchKernelGGL(k_main, dim3(256), dim3(512), 0, stream,
                     LW2T, BB00, BB11, BB01, BB10, H, H2, X0, X1, (float*)d_out);
}